// Round 11
// baseline (248.027 us; speedup 1.0000x reference)
//
#include <hip/hip_runtime.h>

typedef unsigned short u16;
typedef unsigned int u32;
typedef short short8 __attribute__((ext_vector_type(8)));
typedef float f32x4 __attribute__((ext_vector_type(4)));
typedef float f32x16 __attribute__((ext_vector_type(16)));

#define NTOK 2009
#define M8   8036      // 4*2009
#define DMOD 1024
// packed fragment buffers: [bh][tile(63)][...][256] u16; 2048 u16 per tile
#define PKBH 129024    // 63*2048 u16 per bh

static __device__ __forceinline__ u16 f2bf(float f) {
  unsigned int x = __float_as_uint(f);
  x += 0x7fffu + ((x >> 16) & 1u);
  return (u16)(x >> 16);
}
static __device__ __forceinline__ float bf2f(u16 u) {
  return __uint_as_float((unsigned int)u << 16);
}
static __device__ __forceinline__ u32 pk2(float a, float b) {
  return (u32)f2bf(a) | ((u32)f2bf(b) << 16);
}
static __device__ __forceinline__ u32 cvtpk(float a, float b) {
  u32 d;
  asm("v_cvt_pk_bf16_f32 %0, %1, %2" : "=v"(d) : "v"(a), "v"(b));
  return d;
}
static __device__ __forceinline__ void gload_lds16(const void* g, void* l) {
  __builtin_amdgcn_global_load_lds(
      (const __attribute__((address_space(1))) void*)g,
      (__attribute__((address_space(3))) void*)l, 16, 0, 0);
}

// ---------------- merged converts (one launch) ----------------
__global__ void k_convs(const float* __restrict__ x, u16* __restrict__ xb,
                        const float* __restrict__ Wqkv, const float* __restrict__ Wqs,
                        u16* __restrict__ WtCat,
                        const float* __restrict__ Wout, u16* __restrict__ WtOut) {
  int blk = blockIdx.x;
  if (blk < 8036) {
    int i = blk * 256 + threadIdx.x;
    float4 v = ((const float4*)x)[i];
    unsigned int a = (unsigned int)f2bf(v.x) | ((unsigned int)f2bf(v.y) << 16);
    unsigned int b = (unsigned int)f2bf(v.z) | ((unsigned int)f2bf(v.w) << 16);
    ((uint2*)xb)[i] = make_uint2(a, b);
  } else if (blk < 8036 + 5120) {
    int i = (blk - 8036) * 256 + threadIdx.x;
    int n = i >> 10, k = i & 1023;
    float v = (n < 768) ? Wqkv[k * 768 + n] : Wqs[k * 512 + (n - 768)];
    WtCat[i] = f2bf(v);
  } else {
    int i = (blk - 8036 - 5120) * 256 + threadIdx.x;
    int n = i >> 8, k = i & 255;
    WtOut[i] = f2bf(Wout[k * 1024 + n]);
  }
}

// ---------------- projection GEMM (m97-style): [8036,1024] x [1280,1024]^T ----
__global__ __launch_bounds__(256) void k_gemm_proj(
    const u16* __restrict__ A, const u16* __restrict__ Bt,
    u16* __restrict__ Qp, u16* __restrict__ Kp, u16* __restrict__ Vp,
    u16* __restrict__ Qsb, u16* __restrict__ Ksb)
{
  __shared__ u16 Asm[128 * 64];
  __shared__ u16 Bsm[128 * 64];
  int mt = blockIdx.x * 128, nt = blockIdx.y * 128;
  int tid = threadIdx.x, lane = tid & 63, w = tid >> 6;
  int wm = w >> 1, wn = w & 1;
  int fr = lane & 15, fq = lane >> 4;
  int srow = w * 32 + (lane >> 3);
  int scol = (lane & 7) * 8;
  f32x4 acc[4][4];
#pragma unroll
  for (int a = 0; a < 4; ++a)
#pragma unroll
    for (int b = 0; b < 4; ++b) acc[a][b] = (f32x4){0.f, 0.f, 0.f, 0.f};

  for (int kt = 0; kt < 1024; kt += 64) {
#pragma unroll
    for (int j = 0; j < 4; ++j) {
      int r = srow + j * 8;
      int am = mt + r; if (am >= M8) am = 0;
      gload_lds16(A + (size_t)am * 1024 + kt + scol, Asm + (size_t)(w * 32 + j * 8) * 64);
      gload_lds16(Bt + (size_t)(nt + r) * 1024 + kt + scol, Bsm + (size_t)(w * 32 + j * 8) * 64);
    }
    __syncthreads();
#pragma unroll
    for (int cs = 0; cs < 2; ++cs) {
      short8 af[4], bf[4];
#pragma unroll
      for (int i = 0; i < 4; ++i) {
        af[i] = *(const short8*)&Asm[(size_t)(wm * 64 + i * 16 + fr) * 64 + cs * 32 + fq * 8];
        bf[i] = *(const short8*)&Bsm[(size_t)(wn * 64 + i * 16 + fr) * 64 + cs * 32 + fq * 8];
      }
#pragma unroll
      for (int mi = 0; mi < 4; ++mi)
#pragma unroll
        for (int ni = 0; ni < 4; ++ni)
          acc[mi][ni] = __builtin_amdgcn_mfma_f32_16x16x32_bf16(af[mi], bf[ni], acc[mi][ni], 0, 0, 0);
    }
    __syncthreads();
  }

#pragma unroll
  for (int ni = 0; ni < 4; ++ni) {
    int n = nt + wn * 64 + ni * 16 + fr;
    int g = n >> 6, d = n & 63;
    int h = g & 3, sel = g >> 2;   // 0=q 1=k 2=v 3=qs 4=ks
    float scl = (sel == 0 || sel == 3) ? 0.0625f : 1.0f;
#pragma unroll
    for (int mi = 0; mi < 4; ++mi) {
#pragma unroll
      for (int i = 0; i < 4; ++i) {
        int m = mt + wm * 64 + mi * 16 + fq * 4 + i;
        if (m >= M8) continue;
        int b_ = m / NTOK, tok = m - b_ * NTOK;
        int bh = b_ * 4 + h;
        u16 val = f2bf(acc[mi][ni][i] * scl);
        if (sel <= 1) {
          u16* dst = sel == 0 ? Qp : Kp;
          size_t idx = ((((size_t)bh * 63 + (tok >> 5)) * 4 + (d >> 4)) * 2 + ((d >> 3) & 1)) * 256
                       + (tok & 31) * 8 + (d & 7);
          dst[idx] = val;
        } else if (sel == 2) {
          size_t idx = (((((size_t)bh * 63 + (tok >> 5)) * 2 + (d >> 5)) * 2 + ((tok >> 4) & 1)) * 2
                        + ((tok >> 3) & 1)) * 256 + (d & 31) * 8 + (tok & 7);
          Vp[idx] = val;
        } else {
          u16* p = (sel == 3) ? Qsb : Ksb;
          p[((size_t)bh * NTOK + tok) * 64 + d] = val;
        }
      }
    }
  }
}

// ---------------- block-diagonal self dots (Qs pre-scaled) ----------------
__global__ void k_self(const u16* __restrict__ Qs, const u16* __restrict__ Ks,
                       float* __restrict__ selfS) {
  int blk = blockIdx.x;            // bh*200 + agent
  int bh = blk / 200, a = blk % 200;
  int t = threadIdx.x;
  if (t >= 100) return;
  int ri = t / 10, rj = t % 10;
  const u16* qp = &Qs[((size_t)bh * NTOK + a * 10 + ri) * 64];
  const u16* kp = &Ks[((size_t)bh * NTOK + a * 10 + rj) * 64];
  float s = 0.f;
#pragma unroll 8
  for (int k = 0; k < 64; ++k) s += bf2f(qp[k]) * bf2f(kp[k]);
  selfS[(size_t)blk * 100 + t] = s;
}

// ---------------- fused attention v11: 16 waves, pb[4][8], 4 waves/SIMD ----
// 1024-thread block per (bh, 32 q-rows); wave w owns k-tiles
// [w*4, min(w*4+4,63)). Small per-wave state (pb 32 regs) -> <=128 VGPR ->
// 4 waves/SIMD (2x TLP vs prior 2/SIMD cap). Loop1: loads+QK+exp+pack+PV.
// Sum exchange. Loop2: staged row-run stores. O combined via two-phase LDS.
__global__ __launch_bounds__(1024, 4) void k_attn11(
    const u16* __restrict__ Qp, const u16* __restrict__ Kp,
    const u16* __restrict__ Vp, const float* __restrict__ selfS,
    float* __restrict__ attn, u16* __restrict__ Ob)
{
  __shared__ float s_sum[16][32];
  __shared__ float s_inv[32];
  __shared__ float s_o[8][64][32];   // 64 KB; also the per-wave store slabs
  int bh = blockIdx.x;
  int qt = blockIdx.y;
  int q0 = qt * 32;
  int tid = threadIdx.x;
  int lane = tid & 63, w = tid >> 6;          // w in 0..15
  int ql = lane & 31, h = lane >> 5;
  int qg = q0 + ql;
  int lo8 = ql * 8;

  const u16* qbase = Qp + (size_t)bh * PKBH + (size_t)qt * 2048;
  const u16* kbase = Kp + (size_t)bh * PKBH;
  const u16* vbase = Vp + (size_t)bh * PKBH;

  short8 qf[4];
#pragma unroll
  for (int c = 0; c < 4; ++c)
    qf[c] = *(const short8*)&qbase[(c * 2 + h) * 256 + lo8];

  // block-diagonal patch band
  int qa = (qg < 2000) ? (qg / 10) : -1;
  int band_lo = 1 << 30, band_hi = -(1 << 30);
  if (q0 < 2000) {
    int hi_row = (q0 + 31 < 1999) ? q0 + 31 : 1999;
    band_lo = (q0 / 10) * 10;
    band_hi = (hi_row / 10) * 10 + 10;
  }
  const float* sfb = &selfS[(size_t)bh * 20000];

  int t0 = w * 4;
  int t1 = t0 + 4; if (t1 > 63) t1 = 63;

  u32 pb[4][8];                  // packed unnormalized e (bf16 pairs)
  short8 kf[4], kfn[4], vf[4];
  f32x16 oacc0 = {}, oacc1 = {};

  // ====== loop 1: loads + QK + exp + pack + PV (no global stores) ========
#pragma unroll
  for (int c = 0; c < 4; ++c)
    kf[c] = *(const short8*)&kbase[(size_t)t0 * 2048 + (c * 2 + h) * 256 + lo8];
  float ssum = 0.f;
#pragma unroll
  for (int i = 0; i < 4; ++i) {
    int t = t0 + i;
    if (t < t1) {
      int tn = (t + 1 < t1) ? t + 1 : t0;
#pragma unroll
      for (int c = 0; c < 4; ++c)
        vf[c] = *(const short8*)&vbase[(size_t)t * 2048 + (c * 2 + h) * 256 + lo8];
#pragma unroll
      for (int c = 0; c < 4; ++c)
        kfn[c] = *(const short8*)&kbase[(size_t)tn * 2048 + (c * 2 + h) * 256 + lo8];
      f32x16 acc = {};
#pragma unroll
      for (int c = 0; c < 4; ++c)
        acc = __builtin_amdgcn_mfma_f32_32x32x16_bf16(kf[c], qf[c], acc, 0, 0, 0);
      int kt = t * 32;
      float e[16];
      if ((kt < band_hi) && (kt + 32 > band_lo)) {
#pragma unroll
        for (int r = 0; r < 16; ++r) {
          int kc = kt + (r & 3) + 8 * (r >> 2) + 4 * h;
          float sc = acc[r];
          if (qa >= 0 && kc < 2000 && (kc / 10) == qa)
            sc = sfb[qa * 100 + (qg - qa * 10) * 10 + (kc - qa * 10)];
          e[r] = __expf(sc);
        }
      } else {
#pragma unroll
        for (int r = 0; r < 16; ++r) e[r] = __expf(acc[r]);
      }
      if (t == 62) {             // mask k-pad [2009,2016)
#pragma unroll
        for (int r = 0; r < 16; ++r) {
          int kc = kt + (r & 3) + 8 * (r >> 2) + 4 * h;
          if (kc >= NTOK) e[r] = 0.f;
        }
      }
#pragma unroll
      for (int r2 = 0; r2 < 8; ++r2) {
        pb[i][r2] = cvtpk(e[2 * r2], e[2 * r2 + 1]);
        ssum += e[2 * r2] + e[2 * r2 + 1];
      }
      // ---- redistribute pb -> PV B-fragments; PV accumulate ----
      u32 p00 = __shfl_xor(pb[i][0], 32), p01 = __shfl_xor(pb[i][1], 32);
      u32 p10 = __shfl_xor(pb[i][2], 32), p11 = __shfl_xor(pb[i][3], 32);
      u32 p20 = __shfl_xor(pb[i][4], 32), p21 = __shfl_xor(pb[i][5], 32);
      u32 p30 = __shfl_xor(pb[i][6], 32), p31 = __shfl_xor(pb[i][7], 32);
      u32 b0[4], b1[4];
      b0[0] = h ? p10 : pb[i][0];  b0[1] = h ? p11 : pb[i][1];
      b0[2] = h ? pb[i][2] : p00;  b0[3] = h ? pb[i][3] : p01;
      b1[0] = h ? p30 : pb[i][4];  b1[1] = h ? p31 : pb[i][5];
      b1[2] = h ? pb[i][6] : p20;  b1[3] = h ? pb[i][7] : p21;
      short8 B0, B1;
      __builtin_memcpy(&B0, b0, 16);
      __builtin_memcpy(&B1, b1, 16);
      oacc0 = __builtin_amdgcn_mfma_f32_32x32x16_bf16(vf[0], B0, oacc0, 0, 0, 0);
      oacc1 = __builtin_amdgcn_mfma_f32_32x32x16_bf16(vf[2], B0, oacc1, 0, 0, 0);
      oacc0 = __builtin_amdgcn_mfma_f32_32x32x16_bf16(vf[1], B1, oacc0, 0, 0, 0);
      oacc1 = __builtin_amdgcn_mfma_f32_32x32x16_bf16(vf[3], B1, oacc1, 0, 0, 0);
#pragma unroll
      for (int c = 0; c < 4; ++c) kf[c] = kfn[c];
    }
  }
  ssum += __shfl_xor(ssum, 32);
  if (lane < 32) s_sum[w][ql] = ssum;
  __syncthreads();
  if (tid < 32) {
    float tot = 0.f;
#pragma unroll
    for (int s = 0; s < 16; ++s) tot += s_sum[s][tid];
    s_inv[tid] = 1.0f / tot;
  }
  __syncthreads();

  // ====== loop 2: staged row-run store stream ============================
  // per wave: 2 chunks of 2 tiles; 4 KB slab at s_o base + w*4096.
  u32* stage = (u32*)(((char*)s_o) + w * 4096);   // [32 rows][32 u32]
#pragma unroll
  for (int cs = 0; cs < 2; ++cs) {
#pragma unroll
    for (int i2 = 0; i2 < 2; ++i2) {
      int t = t0 + cs * 2 + i2;
      if (t < t1) {
#pragma unroll
        for (int r2 = 0; r2 < 8; ++r2) {
          int c = i2 * 16 + ((r2 & 1) + 4 * (r2 >> 1) + 2 * h);  // pair index
          stage[ql * 32 + (c ^ (ql & 31))] = pb[cs * 2 + i2][r2];
        }
      }
    }
    // write 32 rows x 64 consecutive dwords (one instr per row)
#pragma unroll
    for (int R = 0; R < 32; ++R) {
      int grow = q0 + R;
      int col = t0 * 32 + cs * 64 + lane;
      if (grow < NTOK && col < NTOK) {
        u32 u = stage[R * 32 + (((lane >> 1)) ^ (R & 31))];
        float f = __uint_as_float((lane & 1) ? (u & 0xffff0000u) : (u << 16)) * s_inv[R];
        attn[((size_t)bh * NTOK + grow) * NTOK + col] = f;
      }
    }
  }
  __syncthreads();   // slabs dead; s_o reused for O combine

  // ---- combine partial O: waves 8-15 write, waves 0-7 add, then reduce ----
  if (w >= 8) {
#pragma unroll
    for (int r = 0; r < 16; ++r) {
      int d = (r & 3) + 8 * (r >> 2) + 4 * h;
      s_o[w - 8][d][ql] = oacc0[r];
      s_o[w - 8][d + 32][ql] = oacc1[r];
    }
  }
  __syncthreads();
  if (w < 8) {
#pragma unroll
    for (int r = 0; r < 16; ++r) {
      int d = (r & 3) + 8 * (r >> 2) + 4 * h;
      s_o[w][d][ql] += oacc0[r];
      s_o[w][d + 32][ql] += oacc1[r];
    }
  }
  __syncthreads();
  {
    int q = tid & 31, dp = tid >> 5;          // dp in 0..31 -> d = 2*dp
    int qg2 = q0 + q;
    if (qg2 < NTOK) {
      float invq = s_inv[q];
      int d = dp * 2;
      float a = 0.f, b = 0.f;
#pragma unroll
      for (int s = 0; s < 8; ++s) { a += s_o[s][d][q]; b += s_o[s][d + 1][q]; }
      int b_ = bh >> 2, hd = bh & 3;
      u32* orow = (u32*)&Ob[((size_t)(b_ * NTOK + qg2)) * 256 + hd * 64];
      orow[dp] = pk2(a * invq, b * invq);
    }
  }
}

// ---------------- output GEMM (m97-style): [8036,256] x [1024,256]^T + bias --
__global__ __launch_bounds__(256) void k_gemm_out(
    const u16* __restrict__ A, const u16* __restrict__ Bt,
    const float* __restrict__ bias, float* __restrict__ C)
{
  __shared__ u16 Asm[128 * 64];
  __shared__ u16 Bsm[128 * 64];
  int mt = blockIdx.x * 128, nt = blockIdx.y * 128;
  int tid = threadIdx.x, lane = tid & 63, w = tid >> 6;
  int wm = w >> 1, wn = w & 1;
  int fr = lane & 15, fq = lane >> 4;
  int srow = w * 32 + (lane >> 3);
  int scol = (lane & 7) * 8;
  f32x4 acc[4][4];
#pragma unroll
  for (int a = 0; a < 4; ++a)
#pragma unroll
    for (int b = 0; b < 4; ++b) acc[a][b] = (f32x4){0.f, 0.f, 0.f, 0.f};

  for (int kt = 0; kt < 256; kt += 64) {
#pragma unroll
    for (int j = 0; j < 4; ++j) {
      int r = srow + j * 8;
      int am = mt + r; if (am >= M8) am = 0;
      gload_lds16(A + (size_t)am * 256 + kt + scol, Asm + (size_t)(w * 32 + j * 8) * 64);
      gload_lds16(Bt + (size_t)(nt + r) * 256 + kt + scol, Bsm + (size_t)(w * 32 + j * 8) * 64);
    }
    __syncthreads();
#pragma unroll
    for (int cs = 0; cs < 2; ++cs) {
      short8 af[4], bf[4];
#pragma unroll
      for (int i = 0; i < 4; ++i) {
        af[i] = *(const short8*)&Asm[(size_t)(wm * 64 + i * 16 + fr) * 64 + cs * 32 + fq * 8];
        bf[i] = *(const short8*)&Bsm[(size_t)(wn * 64 + i * 16 + fr) * 64 + cs * 32 + fq * 8];
      }
#pragma unroll
      for (int mi = 0; mi < 4; ++mi)
#pragma unroll
        for (int ni = 0; ni < 4; ++ni)
          acc[mi][ni] = __builtin_amdgcn_mfma_f32_16x16x32_bf16(af[mi], bf[ni], acc[mi][ni], 0, 0, 0);
    }
    __syncthreads();
  }

#pragma unroll
  for (int ni = 0; ni < 4; ++ni) {
    int n = nt + wn * 64 + ni * 16 + fr;
    float bn = bias[n];
#pragma unroll
    for (int mi = 0; mi < 4; ++mi)
#pragma unroll
      for (int i = 0; i < 4; ++i) {
        int m = mt + wm * 64 + mi * 16 + fq * 4 + i;
        if (m < M8) C[(size_t)m * DMOD + n] = acc[mi][ni][i] + bn;
      }
  }
}

extern "C" void kernel_launch(void* const* d_in, const int* in_sizes, int n_in,
                              void* d_out, int out_size, void* d_ws, size_t ws_size,
                              hipStream_t stream) {
  (void)in_sizes; (void)n_in; (void)out_size; (void)ws_size;
  const float* x    = (const float*)d_in[0];
  const float* Wqkv = (const float*)d_in[1];
  const float* Wqs  = (const float*)d_in[2];
  const float* Wout = (const float*)d_in[3];
  const float* bout = (const float*)d_in[4];
  float* out  = (float*)d_out;
  float* attn = out + (size_t)M8 * DMOD;

  char* ws = (char*)d_ws;
  u16*   xb    = (u16*)(ws);                      // 16,457,728
  u16*   WtCat = (u16*)(ws + 16457728);           //  2,621,440
  u16*   WtOut = (u16*)(ws + 19079168);           //    524,288
  u16*   Qp    = (u16*)(ws + 19603456);           //  4,128,768
  u16*   Kp    = (u16*)(ws + 23732224);           //  4,128,768
  u16*   Vp    = (u16*)(ws + 27860992);           //  4,128,768
  u16*   Qsb   = (u16*)(ws + 31989760);           //  4,114,432
  u16*   Ksb   = (u16*)(ws + 36104192);           //  4,114,432
  u16*   Ob    = (u16*)(ws + 40218624);           //  4,114,432
  float* selfS = (float*)(ws + 44333056);         //  1,280,000 (end ~45.6 MB)

  k_convs<<<dim3(8036 + 5120 + 1024), dim3(256), 0, stream>>>(
      x, xb, Wqkv, Wqs, WtCat, Wout, WtOut);
  k_gemm_proj<<<dim3(63, 10), dim3(256), 0, stream>>>(xb, WtCat, Qp, Kp, Vp, Qsb, Ksb);
  k_self<<<dim3(3200), dim3(128), 0, stream>>>(Qsb, Ksb, selfS);
  k_attn11<<<dim3(16, 63), dim3(1024), 0, stream>>>(Qp, Kp, Vp, selfS, attn, Ob);
  k_gemm_out<<<dim3(63, 8), dim3(256), 0, stream>>>(Ob, WtOut, bout, out);
}

// Round 12
// 232.108 us; speedup vs baseline: 1.0686x; 1.0686x over previous
//
#include <hip/hip_runtime.h>

typedef unsigned short u16;
typedef unsigned int u32;
typedef short short8 __attribute__((ext_vector_type(8)));
typedef float f32x4 __attribute__((ext_vector_type(4)));
typedef float f32x16 __attribute__((ext_vector_type(16)));
typedef float float4a __attribute__((ext_vector_type(4), aligned(4)));

#define NTOK 2009
#define M8   8036      // 4*2009
#define DMOD 1024
// packed fragment buffers: [bh][tile(63)][...][256] u16; 2048 u16 per tile
#define PKBH 129024    // 63*2048 u16 per bh

static __device__ __forceinline__ u16 f2bf(float f) {
  unsigned int x = __float_as_uint(f);
  x += 0x7fffu + ((x >> 16) & 1u);
  return (u16)(x >> 16);
}
static __device__ __forceinline__ float bf2f(u16 u) {
  return __uint_as_float((unsigned int)u << 16);
}
static __device__ __forceinline__ u32 pk2(float a, float b) {
  return (u32)f2bf(a) | ((u32)f2bf(b) << 16);
}
static __device__ __forceinline__ u32 cvtpk(float a, float b) {
  u32 d;
  asm("v_cvt_pk_bf16_f32 %0, %1, %2" : "=v"(d) : "v"(a), "v"(b));
  return d;
}
static __device__ __forceinline__ void gload_lds16(const void* g, void* l) {
  __builtin_amdgcn_global_load_lds(
      (const __attribute__((address_space(1))) void*)g,
      (__attribute__((address_space(3))) void*)l, 16, 0, 0);
}

// ---------------- merged converts (one launch) ----------------
__global__ void k_convs(const float* __restrict__ x, u16* __restrict__ xb,
                        const float* __restrict__ Wqkv, const float* __restrict__ Wqs,
                        u16* __restrict__ WtCat,
                        const float* __restrict__ Wout, u16* __restrict__ WtOut) {
  int blk = blockIdx.x;
  if (blk < 8036) {
    int i = blk * 256 + threadIdx.x;
    float4 v = ((const float4*)x)[i];
    unsigned int a = (unsigned int)f2bf(v.x) | ((unsigned int)f2bf(v.y) << 16);
    unsigned int b = (unsigned int)f2bf(v.z) | ((unsigned int)f2bf(v.w) << 16);
    ((uint2*)xb)[i] = make_uint2(a, b);
  } else if (blk < 8036 + 5120) {
    int i = (blk - 8036) * 256 + threadIdx.x;
    int n = i >> 10, k = i & 1023;
    float v = (n < 768) ? Wqkv[k * 768 + n] : Wqs[k * 512 + (n - 768)];
    WtCat[i] = f2bf(v);
  } else {
    int i = (blk - 8036 - 5120) * 256 + threadIdx.x;
    int n = i >> 8, k = i & 255;
    WtOut[i] = f2bf(Wout[k * 1024 + n]);
  }
}

// ---------------- projection GEMM (m97-style): [8036,1024] x [1280,1024]^T ----
__global__ __launch_bounds__(256) void k_gemm_proj(
    const u16* __restrict__ A, const u16* __restrict__ Bt,
    u16* __restrict__ Qp, u16* __restrict__ Kp, u16* __restrict__ Vp,
    u16* __restrict__ Qsb, u16* __restrict__ Ksb)
{
  __shared__ u16 Asm[128 * 64];
  __shared__ u16 Bsm[128 * 64];
  int mt = blockIdx.x * 128, nt = blockIdx.y * 128;
  int tid = threadIdx.x, lane = tid & 63, w = tid >> 6;
  int wm = w >> 1, wn = w & 1;
  int fr = lane & 15, fq = lane >> 4;
  int srow = w * 32 + (lane >> 3);
  int scol = (lane & 7) * 8;
  f32x4 acc[4][4];
#pragma unroll
  for (int a = 0; a < 4; ++a)
#pragma unroll
    for (int b = 0; b < 4; ++b) acc[a][b] = (f32x4){0.f, 0.f, 0.f, 0.f};

  for (int kt = 0; kt < 1024; kt += 64) {
#pragma unroll
    for (int j = 0; j < 4; ++j) {
      int r = srow + j * 8;
      int am = mt + r; if (am >= M8) am = 0;
      gload_lds16(A + (size_t)am * 1024 + kt + scol, Asm + (size_t)(w * 32 + j * 8) * 64);
      gload_lds16(Bt + (size_t)(nt + r) * 1024 + kt + scol, Bsm + (size_t)(w * 32 + j * 8) * 64);
    }
    __syncthreads();
#pragma unroll
    for (int cs = 0; cs < 2; ++cs) {
      short8 af[4], bf[4];
#pragma unroll
      for (int i = 0; i < 4; ++i) {
        af[i] = *(const short8*)&Asm[(size_t)(wm * 64 + i * 16 + fr) * 64 + cs * 32 + fq * 8];
        bf[i] = *(const short8*)&Bsm[(size_t)(wn * 64 + i * 16 + fr) * 64 + cs * 32 + fq * 8];
      }
#pragma unroll
      for (int mi = 0; mi < 4; ++mi)
#pragma unroll
        for (int ni = 0; ni < 4; ++ni)
          acc[mi][ni] = __builtin_amdgcn_mfma_f32_16x16x32_bf16(af[mi], bf[ni], acc[mi][ni], 0, 0, 0);
    }
    __syncthreads();
  }

#pragma unroll
  for (int ni = 0; ni < 4; ++ni) {
    int n = nt + wn * 64 + ni * 16 + fr;
    int g = n >> 6, d = n & 63;
    int h = g & 3, sel = g >> 2;   // 0=q 1=k 2=v 3=qs 4=ks
    float scl = (sel == 0 || sel == 3) ? 0.0625f : 1.0f;
#pragma unroll
    for (int mi = 0; mi < 4; ++mi) {
#pragma unroll
      for (int i = 0; i < 4; ++i) {
        int m = mt + wm * 64 + mi * 16 + fq * 4 + i;
        if (m >= M8) continue;
        int b_ = m / NTOK, tok = m - b_ * NTOK;
        int bh = b_ * 4 + h;
        u16 val = f2bf(acc[mi][ni][i] * scl);
        if (sel <= 1) {
          u16* dst = sel == 0 ? Qp : Kp;
          size_t idx = ((((size_t)bh * 63 + (tok >> 5)) * 4 + (d >> 4)) * 2 + ((d >> 3) & 1)) * 256
                       + (tok & 31) * 8 + (d & 7);
          dst[idx] = val;
        } else if (sel == 2) {
          size_t idx = (((((size_t)bh * 63 + (tok >> 5)) * 2 + (d >> 5)) * 2 + ((tok >> 4) & 1)) * 2
                        + ((tok >> 3) & 1)) * 256 + (d & 31) * 8 + (tok & 7);
          Vp[idx] = val;
        } else {
          u16* p = (sel == 3) ? Qsb : Ksb;
          p[((size_t)bh * NTOK + tok) * 64 + d] = val;
        }
      }
    }
  }
}

// ---------------- block-diagonal self dots (Qs pre-scaled) ----------------
__global__ void k_self(const u16* __restrict__ Qs, const u16* __restrict__ Ks,
                       float* __restrict__ selfS) {
  int blk = blockIdx.x;            // bh*200 + agent
  int bh = blk / 200, a = blk % 200;
  int t = threadIdx.x;
  if (t >= 100) return;
  int ri = t / 10, rj = t % 10;
  const u16* qp = &Qs[((size_t)bh * NTOK + a * 10 + ri) * 64];
  const u16* kp = &Ks[((size_t)bh * NTOK + a * 10 + rj) * 64];
  float s = 0.f;
#pragma unroll 8
  for (int k = 0; k < 64; ++k) s += bf2f(qp[k]) * bf2f(kp[k]);
  selfS[(size_t)blk * 100 + t] = s;
}

// ---------------- sums kernel v2: lean, no prefetch, high occupancy --------
// grid (16 bh, 63 qt, 2); block 256 = 4 waves; wave w -> ks = z*4+w,
// tiles [ks*8, min(+8,63)). Writes partial sums [bh][qt][ks][32].
__global__ __launch_bounds__(256) void k_sums2(
    const u16* __restrict__ Qp, const u16* __restrict__ Kp,
    const float* __restrict__ selfS, float* __restrict__ sums)
{
  int bh = blockIdx.x, qt = blockIdx.y;
  int tid = threadIdx.x, lane = tid & 63, w = tid >> 6;
  int ks = blockIdx.z * 4 + w;
  int ql = lane & 31, h = lane >> 5;
  int q0 = qt * 32, qg = q0 + ql;
  int lo8 = ql * 8;

  const u16* qbase = Qp + (size_t)bh * PKBH + (size_t)qt * 2048;
  const u16* kbase = Kp + (size_t)bh * PKBH;

  short8 qf[4];
#pragma unroll
  for (int c = 0; c < 4; ++c)
    qf[c] = *(const short8*)&qbase[(c * 2 + h) * 256 + lo8];

  int qa = (qg < 2000) ? (qg / 10) : -1;
  int band_lo = 1 << 30, band_hi = -(1 << 30);
  if (q0 < 2000) {
    int hi_row = (q0 + 31 < 1999) ? q0 + 31 : 1999;
    band_lo = (q0 / 10) * 10;
    band_hi = (hi_row / 10) * 10 + 10;
  }
  const float* sfb = &selfS[(size_t)bh * 20000];

  int t0 = ks * 8;
  int t1 = t0 + 8; if (t1 > 63) t1 = 63;

  float ssum = 0.f;
  for (int t = t0; t < t1; ++t) {
    short8 kf[4];
#pragma unroll
    for (int c = 0; c < 4; ++c)
      kf[c] = *(const short8*)&kbase[(size_t)t * 2048 + (c * 2 + h) * 256 + lo8];
    f32x16 acc = {};
#pragma unroll
    for (int c = 0; c < 4; ++c)
      acc = __builtin_amdgcn_mfma_f32_32x32x16_bf16(kf[c], qf[c], acc, 0, 0, 0);
    int kt = t * 32;
    float e[16];
    if ((kt < band_hi) && (kt + 32 > band_lo)) {
#pragma unroll
      for (int r = 0; r < 16; ++r) {
        int kc = kt + (r & 3) + 8 * (r >> 2) + 4 * h;
        float sc = acc[r];
        if (qa >= 0 && kc < 2000 && (kc / 10) == qa)
          sc = sfb[qa * 100 + (qg - qa * 10) * 10 + (kc - qa * 10)];
        e[r] = __expf(sc);
      }
    } else {
#pragma unroll
      for (int r = 0; r < 16; ++r) e[r] = __expf(acc[r]);
    }
    if (t == 62) {
#pragma unroll
      for (int r = 0; r < 16; ++r) {
        int kc = kt + (r & 3) + 8 * (r >> 2) + 4 * h;
        if (kc >= NTOK) e[r] = 0.f;
      }
    }
#pragma unroll
    for (int r = 0; r < 16; ++r) ssum += e[r];
  }
  ssum += __shfl_xor(ssum, 32);
  if (lane < 32) sums[((size_t)(bh * 63 + qt) * 8 + ks) * 32 + ql] = ssum;
}

// ---------------- fused attention v6b: streaming, reg-diet, 3 blocks/CU ----
// Sums precomputed by k_sums2. 4 waves/block, 32 q-rows, wave w owns k-tiles
// [w*16, min(+16,63)). Per tile: V load (top) | K prefetch | QK MFMA -> exp
// -> *inv -> fp32 attn store (wave-private LDS transpose, coalesced) ->
// cvtpk -> PV MFMA (normalized P). One block barrier only for O combine.
__global__ __launch_bounds__(256, 3) void k_attn6b(
    const u16* __restrict__ Qp, const u16* __restrict__ Kp,
    const u16* __restrict__ Vp, const float* __restrict__ selfS,
    const float* __restrict__ sums,
    float* __restrict__ attn, u16* __restrict__ Ob)
{
  __shared__ float s_o[4][64][32];   // 32 KB
  __shared__ float s_p[4][1024];     // 16 KB
  int bh = blockIdx.x;
  int qt = blockIdx.y;
  int q0 = qt * 32;
  int tid = threadIdx.x;
  int lane = tid & 63, w = tid >> 6;
  int ql = lane & 31, h = lane >> 5;
  int qg = q0 + ql;
  int lo8 = ql * 8;

  // row-sum -> inv
  const float* sp = &sums[(size_t)(bh * 63 + qt) * 256 + ql];
  float tot = 0.f;
#pragma unroll
  for (int ks = 0; ks < 8; ++ks) tot += sp[ks * 32];
  float inv = 1.0f / tot;

  const u16* qbase = Qp + (size_t)bh * PKBH + (size_t)qt * 2048;
  const u16* kbase = Kp + (size_t)bh * PKBH;
  const u16* vbase = Vp + (size_t)bh * PKBH;

  short8 qf[4];
#pragma unroll
  for (int c = 0; c < 4; ++c)
    qf[c] = *(const short8*)&qbase[(c * 2 + h) * 256 + lo8];

  int qa = (qg < 2000) ? (qg / 10) : -1;
  int band_lo = 1 << 30, band_hi = -(1 << 30);
  if (q0 < 2000) {
    int hi_row = (q0 + 31 < 1999) ? q0 + 31 : 1999;
    band_lo = (q0 / 10) * 10;
    band_hi = (hi_row / 10) * 10 + 10;
  }
  const float* sfb = &selfS[(size_t)bh * 20000];

  int t0 = w * 16;
  int t1 = t0 + 16; if (t1 > 63) t1 = 63;

  f32x16 oacc0 = {}, oacc1 = {};
  short8 kf[4], kfn[4], vf[4];
#pragma unroll
  for (int c = 0; c < 4; ++c)
    kf[c] = *(const short8*)&kbase[(size_t)t0 * 2048 + (c * 2 + h) * 256 + lo8];
  char* pl = (char*)&s_p[w][0];

  for (int t = t0; t < t1; ++t) {
    int tn = (t + 1 < t1) ? t + 1 : t0;
    // V for this tile (consumed at tile end: covered by QK+exp+stores)
#pragma unroll
    for (int c = 0; c < 4; ++c)
      vf[c] = *(const short8*)&vbase[(size_t)t * 2048 + (c * 2 + h) * 256 + lo8];
    // K prefetch for next tile
#pragma unroll
    for (int c = 0; c < 4; ++c)
      kfn[c] = *(const short8*)&kbase[(size_t)tn * 2048 + (c * 2 + h) * 256 + lo8];
    f32x16 acc = {};
#pragma unroll
    for (int c = 0; c < 4; ++c)
      acc = __builtin_amdgcn_mfma_f32_32x32x16_bf16(kf[c], qf[c], acc, 0, 0, 0);
    int kt = t * 32;
    float p[16];
    if ((kt < band_hi) && (kt + 32 > band_lo)) {
#pragma unroll
      for (int r = 0; r < 16; ++r) {
        int kc = kt + (r & 3) + 8 * (r >> 2) + 4 * h;
        float sc = acc[r];
        if (qa >= 0 && kc < 2000 && (kc / 10) == qa)
          sc = sfb[qa * 100 + (qg - qa * 10) * 10 + (kc - qa * 10)];
        p[r] = __expf(sc);
      }
    } else {
#pragma unroll
      for (int r = 0; r < 16; ++r) p[r] = __expf(acc[r]);
    }
    if (t == 62) {
#pragma unroll
      for (int r = 0; r < 16; ++r) {
        int kc = kt + (r & 3) + 8 * (r >> 2) + 4 * h;
        if (kc >= NTOK) p[r] = 0.f;
      }
    }
#pragma unroll
    for (int r = 0; r < 16; ++r) p[r] *= inv;

    // ---- stage normalized P into swizzled LDS [32 q][32 k] (wave-private) --
#pragma unroll
    for (int rq = 0; rq < 4; ++rq) {
      f32x4 v = {p[4 * rq], p[4 * rq + 1], p[4 * rq + 2], p[4 * rq + 3]};
      *(f32x4*)(pl + ql * 128 + ((rq * 32 + h * 16) ^ ((ql & 7) << 4))) = v;
    }
    // ---- coalesced attn write: 4 instrs, 8 x 128B rows each ----
#pragma unroll
    for (int i2 = 0; i2 < 4; ++i2) {
      int r = i2 * 8 + (lane >> 3), ch = lane & 7;
      f32x4 v = *(f32x4*)(pl + r * 128 + ((ch * 16) ^ ((r & 7) << 4)));
      int grow = q0 + r;
      int col0 = kt + ch * 4;
      if (grow < NTOK) {
        float* arow = &attn[((size_t)bh * NTOK + grow) * NTOK];
        if (col0 + 3 < NTOK) {
          *(float4a*)&arow[col0] = (float4a){v[0], v[1], v[2], v[3]};
        } else {
#pragma unroll
          for (int j = 0; j < 4; ++j)
            if (col0 + j < NTOK) arow[col0 + j] = v[j];
        }
      }
    }

    // ---- P (normalized) -> bf16 B-fragments; PV ----
    u32 pk[8];
#pragma unroll
    for (int r2 = 0; r2 < 8; ++r2) pk[r2] = cvtpk(p[2 * r2], p[2 * r2 + 1]);
    u32 p00 = __shfl_xor(pk[0], 32), p01 = __shfl_xor(pk[1], 32);
    u32 p10 = __shfl_xor(pk[2], 32), p11 = __shfl_xor(pk[3], 32);
    u32 p20 = __shfl_xor(pk[4], 32), p21 = __shfl_xor(pk[5], 32);
    u32 p30 = __shfl_xor(pk[6], 32), p31 = __shfl_xor(pk[7], 32);
    u32 b0[4], b1[4];
    b0[0] = h ? p10 : pk[0];  b0[1] = h ? p11 : pk[1];
    b0[2] = h ? pk[2] : p00;  b0[3] = h ? pk[3] : p01;
    b1[0] = h ? p30 : pk[4];  b1[1] = h ? p31 : pk[5];
    b1[2] = h ? pk[6] : p20;  b1[3] = h ? pk[7] : p21;
    short8 B0, B1;
    __builtin_memcpy(&B0, b0, 16);
    __builtin_memcpy(&B1, b1, 16);
    oacc0 = __builtin_amdgcn_mfma_f32_32x32x16_bf16(vf[0], B0, oacc0, 0, 0, 0);
    oacc1 = __builtin_amdgcn_mfma_f32_32x32x16_bf16(vf[2], B0, oacc1, 0, 0, 0);
    oacc0 = __builtin_amdgcn_mfma_f32_32x32x16_bf16(vf[1], B1, oacc0, 0, 0, 0);
    oacc1 = __builtin_amdgcn_mfma_f32_32x32x16_bf16(vf[3], B1, oacc1, 0, 0, 0);
#pragma unroll
    for (int c = 0; c < 4; ++c) kf[c] = kfn[c];
  }

  // ---- combine partial O across waves via LDS (already normalized) ----
#pragma unroll
  for (int r = 0; r < 16; ++r) {
    int d = (r & 3) + 8 * (r >> 2) + 4 * h;
    s_o[w][d][ql] = oacc0[r];
    s_o[w][d + 32][ql] = oacc1[r];
  }
  __syncthreads();
  {
    int q = tid & 31, dg = tid >> 5;          // 8 d's per thread
    int qg2 = q0 + q;
    if (qg2 < NTOK) {
      int b_ = bh >> 2, hd = bh & 3;
      u16* orow = &Ob[((size_t)(b_ * NTOK + qg2)) * 256 + hd * 64 + dg * 8];
      u32 wpk[4];
#pragma unroll
      for (int j = 0; j < 4; ++j) {
        int d = dg * 8 + 2 * j;
        float a = s_o[0][d][q] + s_o[1][d][q] + s_o[2][d][q] + s_o[3][d][q];
        float b = s_o[0][d + 1][q] + s_o[1][d + 1][q] + s_o[2][d + 1][q] + s_o[3][d + 1][q];
        wpk[j] = pk2(a, b);
      }
      *(uint4*)orow = make_uint4(wpk[0], wpk[1], wpk[2], wpk[3]);
    }
  }
}

// ---------------- output GEMM (m97-style): [8036,256] x [1024,256]^T + bias --
__global__ __launch_bounds__(256) void k_gemm_out(
    const u16* __restrict__ A, const u16* __restrict__ Bt,
    const float* __restrict__ bias, float* __restrict__ C)
{
  __shared__ u16 Asm[128 * 64];
  __shared__ u16 Bsm[128 * 64];
  int mt = blockIdx.x * 128, nt = blockIdx.y * 128;
  int tid = threadIdx.x, lane = tid & 63, w = tid >> 6;
  int wm = w >> 1, wn = w & 1;
  int fr = lane & 15, fq = lane >> 4;
  int srow = w * 32 + (lane >> 3);
  int scol = (lane & 7) * 8;
  f32x4 acc[4][4];
#pragma unroll
  for (int a = 0; a < 4; ++a)
#pragma unroll
    for (int b = 0; b < 4; ++b) acc[a][b] = (f32x4){0.f, 0.f, 0.f, 0.f};

  for (int kt = 0; kt < 256; kt += 64) {
#pragma unroll
    for (int j = 0; j < 4; ++j) {
      int r = srow + j * 8;
      int am = mt + r; if (am >= M8) am = 0;
      gload_lds16(A + (size_t)am * 256 + kt + scol, Asm + (size_t)(w * 32 + j * 8) * 64);
      gload_lds16(Bt + (size_t)(nt + r) * 256 + kt + scol, Bsm + (size_t)(w * 32 + j * 8) * 64);
    }
    __syncthreads();
#pragma unroll
    for (int cs = 0; cs < 2; ++cs) {
      short8 af[4], bf[4];
#pragma unroll
      for (int i = 0; i < 4; ++i) {
        af[i] = *(const short8*)&Asm[(size_t)(wm * 64 + i * 16 + fr) * 64 + cs * 32 + fq * 8];
        bf[i] = *(const short8*)&Bsm[(size_t)(wn * 64 + i * 16 + fr) * 64 + cs * 32 + fq * 8];
      }
#pragma unroll
      for (int mi = 0; mi < 4; ++mi)
#pragma unroll
        for (int ni = 0; ni < 4; ++ni)
          acc[mi][ni] = __builtin_amdgcn_mfma_f32_16x16x32_bf16(af[mi], bf[ni], acc[mi][ni], 0, 0, 0);
    }
    __syncthreads();
  }

#pragma unroll
  for (int ni = 0; ni < 4; ++ni) {
    int n = nt + wn * 64 + ni * 16 + fr;
    float bn = bias[n];
#pragma unroll
    for (int mi = 0; mi < 4; ++mi)
#pragma unroll
      for (int i = 0; i < 4; ++i) {
        int m = mt + wm * 64 + mi * 16 + fq * 4 + i;
        if (m < M8) C[(size_t)m * DMOD + n] = acc[mi][ni][i] + bn;
      }
  }
}

extern "C" void kernel_launch(void* const* d_in, const int* in_sizes, int n_in,
                              void* d_out, int out_size, void* d_ws, size_t ws_size,
                              hipStream_t stream) {
  (void)in_sizes; (void)n_in; (void)out_size; (void)ws_size;
  const float* x    = (const float*)d_in[0];
  const float* Wqkv = (const float*)d_in[1];
  const float* Wqs  = (const float*)d_in[2];
  const float* Wout = (const float*)d_in[3];
  const float* bout = (const float*)d_in[4];
  float* out  = (float*)d_out;
  float* attn = out + (size_t)M8 * DMOD;

  char* ws = (char*)d_ws;
  u16*   xb    = (u16*)(ws);                      // 16,457,728
  u16*   WtCat = (u16*)(ws + 16457728);           //  2,621,440
  u16*   WtOut = (u16*)(ws + 19079168);           //    524,288
  u16*   Qp    = (u16*)(ws + 19603456);           //  4,128,768
  u16*   Kp    = (u16*)(ws + 23732224);           //  4,128,768
  u16*   Vp    = (u16*)(ws + 27860992);           //  4,128,768
  u16*   Qsb   = (u16*)(ws + 31989760);           //  4,114,432
  u16*   Ksb   = (u16*)(ws + 36104192);           //  4,114,432
  u16*   Ob    = (u16*)(ws + 40218624);           //  4,114,432
  float* selfS = (float*)(ws + 44333056);         //  1,280,000 (end ~45.6 MB)
  float* sums  = (float*)(ws);                    //  1,032,192 (reuses xb region;
                                                  //  written only after proj)

  k_convs<<<dim3(8036 + 5120 + 1024), dim3(256), 0, stream>>>(
      x, xb, Wqkv, Wqs, WtCat, Wout, WtOut);
  k_gemm_proj<<<dim3(63, 10), dim3(256), 0, stream>>>(xb, WtCat, Qp, Kp, Vp, Qsb, Ksb);
  k_self<<<dim3(3200), dim3(128), 0, stream>>>(Qsb, Ksb, selfS);
  k_sums2<<<dim3(16, 63, 2), dim3(256), 0, stream>>>(Qp, Kp, selfS, sums);
  k_attn6b<<<dim3(16, 63), dim3(256), 0, stream>>>(Qp, Kp, Vp, selfS, sums, attn, Ob);
  k_gemm_out<<<dim3(63, 8), dim3(256), 0, stream>>>(Ob, WtOut, bout, out);
}

// Round 13
// 196.996 us; speedup vs baseline: 1.2590x; 1.1782x over previous
//
#include <hip/hip_runtime.h>

typedef unsigned short u16;
typedef unsigned int u32;
typedef short short8 __attribute__((ext_vector_type(8)));
typedef float f32x4 __attribute__((ext_vector_type(4)));
typedef float f32x16 __attribute__((ext_vector_type(16)));
typedef float float4a __attribute__((ext_vector_type(4), aligned(4)));

#define NTOK 2009
#define M8   8036      // 4*2009
#define DMOD 1024
// packed fragment buffers: [bh][tile(63)][...][256] u16; 2048 u16 per tile
#define PKBH 129024    // 63*2048 u16 per bh

static __device__ __forceinline__ u16 f2bf(float f) {
  unsigned int x = __float_as_uint(f);
  x += 0x7fffu + ((x >> 16) & 1u);
  return (u16)(x >> 16);
}
static __device__ __forceinline__ float bf2f(u16 u) {
  return __uint_as_float((unsigned int)u << 16);
}
static __device__ __forceinline__ u32 pk2(float a, float b) {
  return (u32)f2bf(a) | ((u32)f2bf(b) << 16);
}
static __device__ __forceinline__ u32 cvtpk(float a, float b) {
  u32 d;
  asm("v_cvt_pk_bf16_f32 %0, %1, %2" : "=v"(d) : "v"(a), "v"(b));
  return d;
}
static __device__ __forceinline__ void gload_lds16(const void* g, void* l) {
  __builtin_amdgcn_global_load_lds(
      (const __attribute__((address_space(1))) void*)g,
      (__attribute__((address_space(3))) void*)l, 16, 0, 0);
}

// ---------------- merged converts (one launch) ----------------
__global__ void k_convs(const float* __restrict__ x, u16* __restrict__ xb,
                        const float* __restrict__ Wqkv, const float* __restrict__ Wqs,
                        u16* __restrict__ WtCat,
                        const float* __restrict__ Wout, u16* __restrict__ WtOut) {
  int blk = blockIdx.x;
  if (blk < 8036) {
    int i = blk * 256 + threadIdx.x;
    float4 v = ((const float4*)x)[i];
    unsigned int a = (unsigned int)f2bf(v.x) | ((unsigned int)f2bf(v.y) << 16);
    unsigned int b = (unsigned int)f2bf(v.z) | ((unsigned int)f2bf(v.w) << 16);
    ((uint2*)xb)[i] = make_uint2(a, b);
  } else if (blk < 8036 + 5120) {
    int i = (blk - 8036) * 256 + threadIdx.x;
    int n = i >> 10, k = i & 1023;
    float v = (n < 768) ? Wqkv[k * 768 + n] : Wqs[k * 512 + (n - 768)];
    WtCat[i] = f2bf(v);
  } else {
    int i = (blk - 8036 - 5120) * 256 + threadIdx.x;
    int n = i >> 8, k = i & 255;
    WtOut[i] = f2bf(Wout[k * 1024 + n]);
  }
}

// ---------------- projection GEMM (m97-style): [8036,1024] x [1280,1024]^T ----
__global__ __launch_bounds__(256) void k_gemm_proj(
    const u16* __restrict__ A, const u16* __restrict__ Bt,
    u16* __restrict__ Qp, u16* __restrict__ Kp, u16* __restrict__ Vp,
    u16* __restrict__ Qsb, u16* __restrict__ Ksb)
{
  __shared__ u16 Asm[128 * 64];
  __shared__ u16 Bsm[128 * 64];
  int mt = blockIdx.x * 128, nt = blockIdx.y * 128;
  int tid = threadIdx.x, lane = tid & 63, w = tid >> 6;
  int wm = w >> 1, wn = w & 1;
  int fr = lane & 15, fq = lane >> 4;
  int srow = w * 32 + (lane >> 3);
  int scol = (lane & 7) * 8;
  f32x4 acc[4][4];
#pragma unroll
  for (int a = 0; a < 4; ++a)
#pragma unroll
    for (int b = 0; b < 4; ++b) acc[a][b] = (f32x4){0.f, 0.f, 0.f, 0.f};

  for (int kt = 0; kt < 1024; kt += 64) {
#pragma unroll
    for (int j = 0; j < 4; ++j) {
      int r = srow + j * 8;
      int am = mt + r; if (am >= M8) am = 0;
      gload_lds16(A + (size_t)am * 1024 + kt + scol, Asm + (size_t)(w * 32 + j * 8) * 64);
      gload_lds16(Bt + (size_t)(nt + r) * 1024 + kt + scol, Bsm + (size_t)(w * 32 + j * 8) * 64);
    }
    __syncthreads();
#pragma unroll
    for (int cs = 0; cs < 2; ++cs) {
      short8 af[4], bf[4];
#pragma unroll
      for (int i = 0; i < 4; ++i) {
        af[i] = *(const short8*)&Asm[(size_t)(wm * 64 + i * 16 + fr) * 64 + cs * 32 + fq * 8];
        bf[i] = *(const short8*)&Bsm[(size_t)(wn * 64 + i * 16 + fr) * 64 + cs * 32 + fq * 8];
      }
#pragma unroll
      for (int mi = 0; mi < 4; ++mi)
#pragma unroll
        for (int ni = 0; ni < 4; ++ni)
          acc[mi][ni] = __builtin_amdgcn_mfma_f32_16x16x32_bf16(af[mi], bf[ni], acc[mi][ni], 0, 0, 0);
    }
    __syncthreads();
  }

#pragma unroll
  for (int ni = 0; ni < 4; ++ni) {
    int n = nt + wn * 64 + ni * 16 + fr;
    int g = n >> 6, d = n & 63;
    int h = g & 3, sel = g >> 2;   // 0=q 1=k 2=v 3=qs 4=ks
    float scl = (sel == 0 || sel == 3) ? 0.0625f : 1.0f;
#pragma unroll
    for (int mi = 0; mi < 4; ++mi) {
#pragma unroll
      for (int i = 0; i < 4; ++i) {
        int m = mt + wm * 64 + mi * 16 + fq * 4 + i;
        if (m >= M8) continue;
        int b_ = m / NTOK, tok = m - b_ * NTOK;
        int bh = b_ * 4 + h;
        u16 val = f2bf(acc[mi][ni][i] * scl);
        if (sel <= 1) {
          u16* dst = sel == 0 ? Qp : Kp;
          size_t idx = ((((size_t)bh * 63 + (tok >> 5)) * 4 + (d >> 4)) * 2 + ((d >> 3) & 1)) * 256
                       + (tok & 31) * 8 + (d & 7);
          dst[idx] = val;
        } else if (sel == 2) {
          size_t idx = (((((size_t)bh * 63 + (tok >> 5)) * 2 + (d >> 5)) * 2 + ((tok >> 4) & 1)) * 2
                        + ((tok >> 3) & 1)) * 256 + (d & 31) * 8 + (tok & 7);
          Vp[idx] = val;
        } else {
          u16* p = (sel == 3) ? Qsb : Ksb;
          p[((size_t)bh * NTOK + tok) * 64 + d] = val;
        }
      }
    }
  }
}

// ---------------- block-diagonal self dots (Qs pre-scaled) ----------------
__global__ void k_self(const u16* __restrict__ Qs, const u16* __restrict__ Ks,
                       float* __restrict__ selfS) {
  int blk = blockIdx.x;            // bh*200 + agent
  int bh = blk / 200, a = blk % 200;
  int t = threadIdx.x;
  if (t >= 100) return;
  int ri = t / 10, rj = t % 10;
  const u16* qp = &Qs[((size_t)bh * NTOK + a * 10 + ri) * 64];
  const u16* kp = &Ks[((size_t)bh * NTOK + a * 10 + rj) * 64];
  float s = 0.f;
#pragma unroll 8
  for (int k = 0; k < 64; ++k) s += bf2f(qp[k]) * bf2f(kp[k]);
  selfS[(size_t)blk * 100 + t] = s;
}

// ---------------- fused attention v13: reg-direct attn stores --------------
// loop1 identical to v8 (loads + QK + exp + cvtpk pack + PV, no stores).
// loop2: unpack pb -> *inv -> 4 independent float4 stores per lane directly
// into the lane's own attn row (no LDS round-trip, no lgkmcnt chains in the
// store stream). Lanes (ql,0)+(ql,1) of one instruction hit the same 128B
// line; the 4 instrs/tile complete each line back-to-back.
__global__ __launch_bounds__(256, 2) void k_attn13(
    const u16* __restrict__ Qp, const u16* __restrict__ Kp,
    const u16* __restrict__ Vp, const float* __restrict__ selfS,
    float* __restrict__ attn, u16* __restrict__ Ob)
{
  __shared__ float s_sum[4][32];
  __shared__ float s_o[4][64][32];   // 32 KB (O combine only)
  int bh = blockIdx.x;
  int qt = blockIdx.y;
  int q0 = qt * 32;
  int tid = threadIdx.x;
  int lane = tid & 63, w = tid >> 6;
  int ql = lane & 31, h = lane >> 5;
  int qg = q0 + ql;
  bool qok = qg < NTOK;
  int qc = qok ? qg : NTOK - 1;
  int lo8 = ql * 8;

  const u16* qbase = Qp + (size_t)bh * PKBH + (size_t)qt * 2048;
  const u16* kbase = Kp + (size_t)bh * PKBH;
  const u16* vbase = Vp + (size_t)bh * PKBH;

  short8 qf[4];
#pragma unroll
  for (int c = 0; c < 4; ++c)
    qf[c] = *(const short8*)&qbase[(c * 2 + h) * 256 + lo8];

  // block-diagonal patch band
  int qa = (qg < 2000) ? (qg / 10) : -1;
  int band_lo = 1 << 30, band_hi = -(1 << 30);
  if (q0 < 2000) {
    int hi_row = (q0 + 31 < 1999) ? q0 + 31 : 1999;
    band_lo = (q0 / 10) * 10;
    band_hi = (hi_row / 10) * 10 + 10;
  }
  const float* sfb = &selfS[(size_t)bh * 20000];

  int t0 = w * 16;
  int t1 = t0 + 16; if (t1 > 63) t1 = 63;

  u32 pb[16][8];                 // packed unnormalized e (bf16 pairs)
  short8 kf[4], kfn[4], vf[4];
  f32x16 oacc0 = {}, oacc1 = {};

  // ====== loop 1: loads + QK + exp + pack + PV (no global stores) ========
#pragma unroll
  for (int c = 0; c < 4; ++c)
    kf[c] = *(const short8*)&kbase[(size_t)t0 * 2048 + (c * 2 + h) * 256 + lo8];
  float ssum = 0.f;
#pragma unroll
  for (int i = 0; i < 16; ++i) {
    int t = t0 + i;
    if (t < t1) {
      int tn = (t + 1 < t1) ? t + 1 : t0;
#pragma unroll
      for (int c = 0; c < 4; ++c)
        vf[c] = *(const short8*)&vbase[(size_t)t * 2048 + (c * 2 + h) * 256 + lo8];
#pragma unroll
      for (int c = 0; c < 4; ++c)
        kfn[c] = *(const short8*)&kbase[(size_t)tn * 2048 + (c * 2 + h) * 256 + lo8];
      f32x16 acc = {};
#pragma unroll
      for (int c = 0; c < 4; ++c)
        acc = __builtin_amdgcn_mfma_f32_32x32x16_bf16(kf[c], qf[c], acc, 0, 0, 0);
      int kt = t * 32;
      float e[16];
      if ((kt < band_hi) && (kt + 32 > band_lo)) {
#pragma unroll
        for (int r = 0; r < 16; ++r) {
          int kc = kt + (r & 3) + 8 * (r >> 2) + 4 * h;
          float sc = acc[r];
          if (qa >= 0 && kc < 2000 && (kc / 10) == qa)
            sc = sfb[qa * 100 + (qg - qa * 10) * 10 + (kc - qa * 10)];
          e[r] = __expf(sc);
        }
      } else {
#pragma unroll
        for (int r = 0; r < 16; ++r) e[r] = __expf(acc[r]);
      }
      if (t == 62) {             // mask k-pad [2009,2016)
#pragma unroll
        for (int r = 0; r < 16; ++r) {
          int kc = kt + (r & 3) + 8 * (r >> 2) + 4 * h;
          if (kc >= NTOK) e[r] = 0.f;
        }
      }
#pragma unroll
      for (int r2 = 0; r2 < 8; ++r2) {
        pb[i][r2] = cvtpk(e[2 * r2], e[2 * r2 + 1]);
        ssum += e[2 * r2] + e[2 * r2 + 1];
      }
      // ---- redistribute pb -> PV B-fragments; PV accumulate ----
      u32 p00 = __shfl_xor(pb[i][0], 32), p01 = __shfl_xor(pb[i][1], 32);
      u32 p10 = __shfl_xor(pb[i][2], 32), p11 = __shfl_xor(pb[i][3], 32);
      u32 p20 = __shfl_xor(pb[i][4], 32), p21 = __shfl_xor(pb[i][5], 32);
      u32 p30 = __shfl_xor(pb[i][6], 32), p31 = __shfl_xor(pb[i][7], 32);
      u32 b0[4], b1[4];
      b0[0] = h ? p10 : pb[i][0];  b0[1] = h ? p11 : pb[i][1];
      b0[2] = h ? pb[i][2] : p00;  b0[3] = h ? pb[i][3] : p01;
      b1[0] = h ? p30 : pb[i][4];  b1[1] = h ? p31 : pb[i][5];
      b1[2] = h ? pb[i][6] : p20;  b1[3] = h ? pb[i][7] : p21;
      short8 B0, B1;
      __builtin_memcpy(&B0, b0, 16);
      __builtin_memcpy(&B1, b1, 16);
      oacc0 = __builtin_amdgcn_mfma_f32_32x32x16_bf16(vf[0], B0, oacc0, 0, 0, 0);
      oacc1 = __builtin_amdgcn_mfma_f32_32x32x16_bf16(vf[2], B0, oacc1, 0, 0, 0);
      oacc0 = __builtin_amdgcn_mfma_f32_32x32x16_bf16(vf[1], B1, oacc0, 0, 0, 0);
      oacc1 = __builtin_amdgcn_mfma_f32_32x32x16_bf16(vf[3], B1, oacc1, 0, 0, 0);
#pragma unroll
      for (int c = 0; c < 4; ++c) kf[c] = kfn[c];
    }
  }
  ssum += __shfl_xor(ssum, 32);
  if (lane < 32) s_sum[w][ql] = ssum;
  __syncthreads();
  float inv = 1.0f / (s_sum[0][ql] + s_sum[1][ql] + s_sum[2][ql] + s_sum[3][ql]);

  // ====== loop 2: direct-from-register store stream ======================
  float* arow = &attn[((size_t)bh * NTOK + qc) * NTOK];
#pragma unroll
  for (int i = 0; i < 16; ++i) {
    int t = t0 + i;
    if (t < t1 && qok) {
      int kt = t * 32;
      float e[16];
#pragma unroll
      for (int r2 = 0; r2 < 8; ++r2) {
        u32 u = pb[i][r2];
        e[2 * r2]     = __uint_as_float(u << 16) * inv;
        e[2 * r2 + 1] = __uint_as_float(u & 0xffff0000u) * inv;
      }
      if (t < 62) {
#pragma unroll
        for (int rq = 0; rq < 4; ++rq) {
          int col0 = kt + 8 * rq + 4 * h;
          *(float4a*)&arow[col0] =
              (float4a){e[4 * rq], e[4 * rq + 1], e[4 * rq + 2], e[4 * rq + 3]};
        }
      } else {
#pragma unroll
        for (int rq = 0; rq < 4; ++rq) {
          int col0 = kt + 8 * rq + 4 * h;
          if (col0 + 3 < NTOK) {
            *(float4a*)&arow[col0] =
                (float4a){e[4 * rq], e[4 * rq + 1], e[4 * rq + 2], e[4 * rq + 3]};
          } else {
#pragma unroll
            for (int j = 0; j < 4; ++j)
              if (col0 + j < NTOK) arow[col0 + j] = e[4 * rq + j];
          }
        }
      }
    }
  }

  // ---- combine partial O across waves via LDS (normalize here) ----
#pragma unroll
  for (int r = 0; r < 16; ++r) {
    int d = (r & 3) + 8 * (r >> 2) + 4 * h;
    s_o[w][d][ql] = oacc0[r];
    s_o[w][d + 32][ql] = oacc1[r];
  }
  __syncthreads();
  {
    int q = tid & 31, dg = tid >> 5;          // 8 d's per thread
    int qg2 = q0 + q;
    if (qg2 < NTOK) {
      float invq = 1.0f / (s_sum[0][q] + s_sum[1][q] + s_sum[2][q] + s_sum[3][q]);
      int b_ = bh >> 2, hd = bh & 3;
      u16* orow = &Ob[((size_t)(b_ * NTOK + qg2)) * 256 + hd * 64 + dg * 8];
      u32 wpk[4];
#pragma unroll
      for (int j = 0; j < 4; ++j) {
        int d = dg * 8 + 2 * j;
        float a = (s_o[0][d][q] + s_o[1][d][q] + s_o[2][d][q] + s_o[3][d][q]) * invq;
        float b = (s_o[0][d + 1][q] + s_o[1][d + 1][q] + s_o[2][d + 1][q] + s_o[3][d + 1][q]) * invq;
        wpk[j] = pk2(a, b);
      }
      *(uint4*)orow = make_uint4(wpk[0], wpk[1], wpk[2], wpk[3]);
    }
  }
}

// ---------------- output GEMM (m97-style): [8036,256] x [1024,256]^T + bias --
__global__ __launch_bounds__(256) void k_gemm_out(
    const u16* __restrict__ A, const u16* __restrict__ Bt,
    const float* __restrict__ bias, float* __restrict__ C)
{
  __shared__ u16 Asm[128 * 64];
  __shared__ u16 Bsm[128 * 64];
  int mt = blockIdx.x * 128, nt = blockIdx.y * 128;
  int tid = threadIdx.x, lane = tid & 63, w = tid >> 6;
  int wm = w >> 1, wn = w & 1;
  int fr = lane & 15, fq = lane >> 4;
  int srow = w * 32 + (lane >> 3);
  int scol = (lane & 7) * 8;
  f32x4 acc[4][4];
#pragma unroll
  for (int a = 0; a < 4; ++a)
#pragma unroll
    for (int b = 0; b < 4; ++b) acc[a][b] = (f32x4){0.f, 0.f, 0.f, 0.f};

  for (int kt = 0; kt < 256; kt += 64) {
#pragma unroll
    for (int j = 0; j < 4; ++j) {
      int r = srow + j * 8;
      int am = mt + r; if (am >= M8) am = 0;
      gload_lds16(A + (size_t)am * 256 + kt + scol, Asm + (size_t)(w * 32 + j * 8) * 64);
      gload_lds16(Bt + (size_t)(nt + r) * 256 + kt + scol, Bsm + (size_t)(w * 32 + j * 8) * 64);
    }
    __syncthreads();
#pragma unroll
    for (int cs = 0; cs < 2; ++cs) {
      short8 af[4], bf[4];
#pragma unroll
      for (int i = 0; i < 4; ++i) {
        af[i] = *(const short8*)&Asm[(size_t)(wm * 64 + i * 16 + fr) * 64 + cs * 32 + fq * 8];
        bf[i] = *(const short8*)&Bsm[(size_t)(wn * 64 + i * 16 + fr) * 64 + cs * 32 + fq * 8];
      }
#pragma unroll
      for (int mi = 0; mi < 4; ++mi)
#pragma unroll
        for (int ni = 0; ni < 4; ++ni)
          acc[mi][ni] = __builtin_amdgcn_mfma_f32_16x16x32_bf16(af[mi], bf[ni], acc[mi][ni], 0, 0, 0);
    }
    __syncthreads();
  }

#pragma unroll
  for (int ni = 0; ni < 4; ++ni) {
    int n = nt + wn * 64 + ni * 16 + fr;
    float bn = bias[n];
#pragma unroll
    for (int mi = 0; mi < 4; ++mi)
#pragma unroll
      for (int i = 0; i < 4; ++i) {
        int m = mt + wm * 64 + mi * 16 + fq * 4 + i;
        if (m < M8) C[(size_t)m * DMOD + n] = acc[mi][ni][i] + bn;
      }
  }
}

extern "C" void kernel_launch(void* const* d_in, const int* in_sizes, int n_in,
                              void* d_out, int out_size, void* d_ws, size_t ws_size,
                              hipStream_t stream) {
  (void)in_sizes; (void)n_in; (void)out_size; (void)ws_size;
  const float* x    = (const float*)d_in[0];
  const float* Wqkv = (const float*)d_in[1];
  const float* Wqs  = (const float*)d_in[2];
  const float* Wout = (const float*)d_in[3];
  const float* bout = (const float*)d_in[4];
  float* out  = (float*)d_out;
  float* attn = out + (size_t)M8 * DMOD;

  char* ws = (char*)d_ws;
  u16*   xb    = (u16*)(ws);                      // 16,457,728
  u16*   WtCat = (u16*)(ws + 16457728);           //  2,621,440
  u16*   WtOut = (u16*)(ws + 19079168);           //    524,288
  u16*   Qp    = (u16*)(ws + 19603456);           //  4,128,768
  u16*   Kp    = (u16*)(ws + 23732224);           //  4,128,768
  u16*   Vp    = (u16*)(ws + 27860992);           //  4,128,768
  u16*   Qsb   = (u16*)(ws + 31989760);           //  4,114,432
  u16*   Ksb   = (u16*)(ws + 36104192);           //  4,114,432
  u16*   Ob    = (u16*)(ws + 40218624);           //  4,114,432
  float* selfS = (float*)(ws + 44333056);         //  1,280,000 (end ~45.6 MB)

  k_convs<<<dim3(8036 + 5120 + 1024), dim3(256), 0, stream>>>(
      x, xb, Wqkv, Wqs, WtCat, Wout, WtOut);
  k_gemm_proj<<<dim3(63, 10), dim3(256), 0, stream>>>(xb, WtCat, Qp, Kp, Vp, Qsb, Ksb);
  k_self<<<dim3(3200), dim3(128), 0, stream>>>(Qsb, Ksb, selfS);
  k_attn13<<<dim3(16, 63), dim3(256), 0, stream>>>(Qp, Kp, Vp, selfS, attn, Ob);
  k_gemm_out<<<dim3(63, 8), dim3(256), 0, stream>>>(Ob, WtOut, bout, out);
}

// Round 14
// 187.186 us; speedup vs baseline: 1.3250x; 1.0524x over previous
//
#include <hip/hip_runtime.h>

typedef unsigned short u16;
typedef unsigned int u32;
typedef short short8 __attribute__((ext_vector_type(8)));
typedef float f32x4 __attribute__((ext_vector_type(4)));
typedef float f32x16 __attribute__((ext_vector_type(16)));
typedef float float4a __attribute__((ext_vector_type(4), aligned(4)));

#define NTOK 2009
#define M8   8036      // 4*2009 (real rows)
#define TOKP 2016      // padded tokens per batch (63*32)
#define M8P  8064      // 4*2016 padded rows
#define DMOD 1024
// packed fragment buffers: [bh][tile(63)][...][256] u16; 2048 u16 per tile
#define PKBH 129024    // 63*2048 u16 per bh

static __device__ __forceinline__ u16 f2bf(float f) {
  unsigned int x = __float_as_uint(f);
  x += 0x7fffu + ((x >> 16) & 1u);
  return (u16)(x >> 16);
}
static __device__ __forceinline__ float bf2f(u16 u) {
  return __uint_as_float((unsigned int)u << 16);
}
static __device__ __forceinline__ u32 pk2(float a, float b) {
  return (u32)f2bf(a) | ((u32)f2bf(b) << 16);
}
static __device__ __forceinline__ u32 cvtpk(float a, float b) {
  u32 d;
  asm("v_cvt_pk_bf16_f32 %0, %1, %2" : "=v"(d) : "v"(a), "v"(b));
  return d;
}
static __device__ __forceinline__ void gload_lds16(const void* g, void* l) {
  __builtin_amdgcn_global_load_lds(
      (const __attribute__((address_space(1))) void*)g,
      (__attribute__((address_space(3))) void*)l, 16, 0, 0);
}

// ---------------- merged converts (one launch); xb padded to [4][2016][1024] --
__global__ void k_convs(const float* __restrict__ x, u16* __restrict__ xb,
                        const float* __restrict__ Wqkv, const float* __restrict__ Wqs,
                        u16* __restrict__ WtCat,
                        const float* __restrict__ Wout, u16* __restrict__ WtOut) {
  int blk = blockIdx.x;
  if (blk < 8064) {
    int i = blk * 256 + threadIdx.x;          // uint2 index over padded xb
    int b = i / (TOKP * 256);
    int rem = i - b * (TOKP * 256);
    int tok = rem >> 8, dg = rem & 255;
    uint2 o = make_uint2(0u, 0u);
    if (tok < NTOK) {
      float4 v = ((const float4*)x)[(size_t)(b * NTOK + tok) * 256 + dg];
      o.x = (u32)f2bf(v.x) | ((u32)f2bf(v.y) << 16);
      o.y = (u32)f2bf(v.z) | ((u32)f2bf(v.w) << 16);
    }
    ((uint2*)xb)[i] = o;
  } else if (blk < 8064 + 5120) {
    int i = (blk - 8064) * 256 + threadIdx.x;
    int n = i >> 10, k = i & 1023;
    float v = (n < 768) ? Wqkv[k * 768 + n] : Wqs[k * 512 + (n - 768)];
    WtCat[i] = f2bf(v);
  } else {
    int i = (blk - 8064 - 5120) * 256 + threadIdx.x;
    int n = i >> 8, k = i & 255;
    WtOut[i] = f2bf(Wout[k * 1024 + n]);
  }
}

// ---------------- projection GEMM: [8064,1024] x [1280,1024]^T --------------
// m97-style k-loop; epilogue restages C tile in LDS (16B-chunk XOR swizzle),
// then coalesced dwordx4 stores in packed-layout order. Blocks are sel-pure
// (sel = nt/256: 0=q 1=k 2=v 3=qs 4=ks); V is dumped transposed.
__global__ __launch_bounds__(256) void k_gemm_proj(
    const u16* __restrict__ A, const u16* __restrict__ Bt,
    u16* __restrict__ Qp, u16* __restrict__ Kp, u16* __restrict__ Vp,
    u16* __restrict__ Qsb, u16* __restrict__ Ksb)
{
  __shared__ u16 smem[2][128 * 64];           // A/B staging; reused as C[128][128]
  u16* Asm = smem[0];
  u16* Bsm = smem[1];
  int mt = blockIdx.x * 128, nt = blockIdx.y * 128;
  int tid = threadIdx.x, lane = tid & 63, w = tid >> 6;
  int wm = w >> 1, wn = w & 1;
  int fr = lane & 15, fq = lane >> 4;
  int srow = w * 32 + (lane >> 3);
  int scol = (lane & 7) * 8;
  f32x4 acc[4][4];
#pragma unroll
  for (int a = 0; a < 4; ++a)
#pragma unroll
    for (int b = 0; b < 4; ++b) acc[a][b] = (f32x4){0.f, 0.f, 0.f, 0.f};

  for (int kt = 0; kt < 1024; kt += 64) {
#pragma unroll
    for (int j = 0; j < 4; ++j) {
      int r = srow + j * 8;
      gload_lds16(A + (size_t)(mt + r) * 1024 + kt + scol, Asm + (size_t)(w * 32 + j * 8) * 64);
      gload_lds16(Bt + (size_t)(nt + r) * 1024 + kt + scol, Bsm + (size_t)(w * 32 + j * 8) * 64);
    }
    __syncthreads();
#pragma unroll
    for (int cs = 0; cs < 2; ++cs) {
      short8 af[4], bf[4];
#pragma unroll
      for (int i = 0; i < 4; ++i) {
        af[i] = *(const short8*)&Asm[(size_t)(wm * 64 + i * 16 + fr) * 64 + cs * 32 + fq * 8];
        bf[i] = *(const short8*)&Bsm[(size_t)(wn * 64 + i * 16 + fr) * 64 + cs * 32 + fq * 8];
      }
#pragma unroll
      for (int mi = 0; mi < 4; ++mi)
#pragma unroll
        for (int ni = 0; ni < 4; ++ni)
          acc[mi][ni] = __builtin_amdgcn_mfma_f32_16x16x32_bf16(af[mi], bf[ni], acc[mi][ni], 0, 0, 0);
    }
    __syncthreads();
  }

  // ---- epilogue: dump acc to LDS C[128][128] (swizzled), sel-pure block ----
  int sel = nt >> 8;                           // 0=q 1=k 2=v 3=qs 4=ks
  float scl = (sel == 0 || sel == 3) ? 0.0625f : 1.0f;
  bool T = (sel == 2);
  u16* Csm = smem[0];                          // 32 KB = [128][128] u16
#pragma unroll
  for (int ni = 0; ni < 4; ++ni) {
#pragma unroll
    for (int mi = 0; mi < 4; ++mi) {
#pragma unroll
      for (int i = 0; i < 4; ++i) {
        int rm = wm * 64 + mi * 16 + fq * 4 + i;     // m-local
        int cn = wn * 64 + ni * 16 + fr;             // n-local
        u16 val = f2bf(acc[mi][ni][i] * scl);
        if (!T) Csm[rm * 128 + (cn ^ ((rm & 7) << 3))] = val;
        else    Csm[cn * 128 + (rm ^ ((cn & 7) << 3))] = val;
      }
    }
  }
  __syncthreads();

  // ---- coalesced packed write-out: 4 row-groups x 2 head-halves ----------
  int t = tid;
#pragma unroll
  for (int rg = 0; rg < 4; ++rg) {
    int row_g = mt + rg * 32;
    int b_ = row_g / TOKP;
    int tok0 = row_g - b_ * TOKP;
    int tile = tok0 >> 5;
#pragma unroll
    for (int g2 = 0; g2 < 2; ++g2) {
      int g = ((nt + g2 * 64) >> 6);
      int h = g & 3;
      int bh = b_ * 4 + h;
      int Lrow, Lcol0;
      if (sel <= 1) {
        Lrow = rg * 32 + (t & 31);
        Lcol0 = g2 * 64 + (t >> 5) * 8;
        short8 v = *(const short8*)&Csm[Lrow * 128 + (Lcol0 ^ ((Lrow & 7) << 3))];
        u16* dst = (sel == 0 ? Qp : Kp) + ((size_t)bh * 63 + tile) * 2048
                   + (t >> 5) * 256 + (t & 31) * 8;
        *(short8*)dst = v;
      } else if (sel == 2) {
        // transposed dump: Csm[d_local(n)][tok_local(m)]
        Lrow = g2 * 64 + (t >> 7) * 32 + (t & 31);          // n-local (d)
        Lcol0 = rg * 32 + ((t >> 5) & 3) * 8;               // m-local (tok)
        short8 v = *(const short8*)&Csm[Lrow * 128 + (Lcol0 ^ ((Lrow & 7) << 3))];
        u16* dst = Vp + ((size_t)bh * 63 + tile) * 2048 + (t >> 5) * 256 + (t & 31) * 8;
        *(short8*)dst = v;
      } else {
        int tok_l = t >> 3;
        int tok_g = tok0 + tok_l;
        if (tok_g < NTOK) {
          Lrow = rg * 32 + tok_l;
          Lcol0 = g2 * 64 + (t & 7) * 8;
          short8 v = *(const short8*)&Csm[Lrow * 128 + (Lcol0 ^ ((Lrow & 7) << 3))];
          u16* dst = (sel == 3 ? Qsb : Ksb) + ((size_t)bh * NTOK + tok_g) * 64 + (t & 7) * 8;
          *(short8*)dst = v;
        }
      }
    }
  }
}

// ---------------- block-diagonal self dots (Qs pre-scaled, vectorized) -----
__global__ void k_self(const u16* __restrict__ Qs, const u16* __restrict__ Ks,
                       float* __restrict__ selfS) {
  int blk = blockIdx.x;            // bh*200 + agent
  int bh = blk / 200, a = blk % 200;
  int t = threadIdx.x;
  if (t >= 100) return;
  int ri = t / 10, rj = t % 10;
  const short8* qv = (const short8*)&Qs[((size_t)bh * NTOK + a * 10 + ri) * 64];
  const short8* kv = (const short8*)&Ks[((size_t)bh * NTOK + a * 10 + rj) * 64];
  float s = 0.f;
#pragma unroll
  for (int c = 0; c < 8; ++c) {
    short8 qa = qv[c], kb = kv[c];
#pragma unroll
    for (int j = 0; j < 8; ++j) s += bf2f((u16)qa[j]) * bf2f((u16)kb[j]);
  }
  selfS[(size_t)blk * 100 + t] = s;
}

// ---------------- fused attention v13: reg-direct attn stores (frozen) -----
__global__ __launch_bounds__(256, 2) void k_attn13(
    const u16* __restrict__ Qp, const u16* __restrict__ Kp,
    const u16* __restrict__ Vp, const float* __restrict__ selfS,
    float* __restrict__ attn, u16* __restrict__ Ob)
{
  __shared__ float s_sum[4][32];
  __shared__ float s_o[4][64][32];   // 32 KB (O combine only)
  int bh = blockIdx.x;
  int qt = blockIdx.y;
  int q0 = qt * 32;
  int tid = threadIdx.x;
  int lane = tid & 63, w = tid >> 6;
  int ql = lane & 31, h = lane >> 5;
  int qg = q0 + ql;
  bool qok = qg < NTOK;
  int qc = qok ? qg : NTOK - 1;
  int lo8 = ql * 8;

  const u16* qbase = Qp + (size_t)bh * PKBH + (size_t)qt * 2048;
  const u16* kbase = Kp + (size_t)bh * PKBH;
  const u16* vbase = Vp + (size_t)bh * PKBH;

  short8 qf[4];
#pragma unroll
  for (int c = 0; c < 4; ++c)
    qf[c] = *(const short8*)&qbase[(c * 2 + h) * 256 + lo8];

  // block-diagonal patch band
  int qa = (qg < 2000) ? (qg / 10) : -1;
  int band_lo = 1 << 30, band_hi = -(1 << 30);
  if (q0 < 2000) {
    int hi_row = (q0 + 31 < 1999) ? q0 + 31 : 1999;
    band_lo = (q0 / 10) * 10;
    band_hi = (hi_row / 10) * 10 + 10;
  }
  const float* sfb = &selfS[(size_t)bh * 20000];

  int t0 = w * 16;
  int t1 = t0 + 16; if (t1 > 63) t1 = 63;

  u32 pb[16][8];                 // packed unnormalized e (bf16 pairs)
  short8 kf[4], kfn[4], vf[4];
  f32x16 oacc0 = {}, oacc1 = {};

  // ====== loop 1: loads + QK + exp + pack + PV (no global stores) ========
#pragma unroll
  for (int c = 0; c < 4; ++c)
    kf[c] = *(const short8*)&kbase[(size_t)t0 * 2048 + (c * 2 + h) * 256 + lo8];
  float ssum = 0.f;
#pragma unroll
  for (int i = 0; i < 16; ++i) {
    int t = t0 + i;
    if (t < t1) {
      int tn = (t + 1 < t1) ? t + 1 : t0;
#pragma unroll
      for (int c = 0; c < 4; ++c)
        vf[c] = *(const short8*)&vbase[(size_t)t * 2048 + (c * 2 + h) * 256 + lo8];
#pragma unroll
      for (int c = 0; c < 4; ++c)
        kfn[c] = *(const short8*)&kbase[(size_t)tn * 2048 + (c * 2 + h) * 256 + lo8];
      f32x16 acc = {};
#pragma unroll
      for (int c = 0; c < 4; ++c)
        acc = __builtin_amdgcn_mfma_f32_32x32x16_bf16(kf[c], qf[c], acc, 0, 0, 0);
      int kt = t * 32;
      float e[16];
      if ((kt < band_hi) && (kt + 32 > band_lo)) {
#pragma unroll
        for (int r = 0; r < 16; ++r) {
          int kc = kt + (r & 3) + 8 * (r >> 2) + 4 * h;
          float sc = acc[r];
          if (qa >= 0 && kc < 2000 && (kc / 10) == qa)
            sc = sfb[qa * 100 + (qg - qa * 10) * 10 + (kc - qa * 10)];
          e[r] = __expf(sc);
        }
      } else {
#pragma unroll
        for (int r = 0; r < 16; ++r) e[r] = __expf(acc[r]);
      }
      if (t == 62) {             // mask k-pad [2009,2016)
#pragma unroll
        for (int r = 0; r < 16; ++r) {
          int kc = kt + (r & 3) + 8 * (r >> 2) + 4 * h;
          if (kc >= NTOK) e[r] = 0.f;
        }
      }
#pragma unroll
      for (int r2 = 0; r2 < 8; ++r2) {
        pb[i][r2] = cvtpk(e[2 * r2], e[2 * r2 + 1]);
        ssum += e[2 * r2] + e[2 * r2 + 1];
      }
      // ---- redistribute pb -> PV B-fragments; PV accumulate ----
      u32 p00 = __shfl_xor(pb[i][0], 32), p01 = __shfl_xor(pb[i][1], 32);
      u32 p10 = __shfl_xor(pb[i][2], 32), p11 = __shfl_xor(pb[i][3], 32);
      u32 p20 = __shfl_xor(pb[i][4], 32), p21 = __shfl_xor(pb[i][5], 32);
      u32 p30 = __shfl_xor(pb[i][6], 32), p31 = __shfl_xor(pb[i][7], 32);
      u32 b0[4], b1[4];
      b0[0] = h ? p10 : pb[i][0];  b0[1] = h ? p11 : pb[i][1];
      b0[2] = h ? pb[i][2] : p00;  b0[3] = h ? pb[i][3] : p01;
      b1[0] = h ? p30 : pb[i][4];  b1[1] = h ? p31 : pb[i][5];
      b1[2] = h ? pb[i][6] : p20;  b1[3] = h ? pb[i][7] : p21;
      short8 B0, B1;
      __builtin_memcpy(&B0, b0, 16);
      __builtin_memcpy(&B1, b1, 16);
      oacc0 = __builtin_amdgcn_mfma_f32_32x32x16_bf16(vf[0], B0, oacc0, 0, 0, 0);
      oacc1 = __builtin_amdgcn_mfma_f32_32x32x16_bf16(vf[2], B0, oacc1, 0, 0, 0);
      oacc0 = __builtin_amdgcn_mfma_f32_32x32x16_bf16(vf[1], B1, oacc0, 0, 0, 0);
      oacc1 = __builtin_amdgcn_mfma_f32_32x32x16_bf16(vf[3], B1, oacc1, 0, 0, 0);
#pragma unroll
      for (int c = 0; c < 4; ++c) kf[c] = kfn[c];
    }
  }
  ssum += __shfl_xor(ssum, 32);
  if (lane < 32) s_sum[w][ql] = ssum;
  __syncthreads();
  float inv = 1.0f / (s_sum[0][ql] + s_sum[1][ql] + s_sum[2][ql] + s_sum[3][ql]);

  // ====== loop 2: direct-from-register store stream ======================
  float* arow = &attn[((size_t)bh * NTOK + qc) * NTOK];
#pragma unroll
  for (int i = 0; i < 16; ++i) {
    int t = t0 + i;
    if (t < t1 && qok) {
      int kt = t * 32;
      float e[16];
#pragma unroll
      for (int r2 = 0; r2 < 8; ++r2) {
        u32 u = pb[i][r2];
        e[2 * r2]     = __uint_as_float(u << 16) * inv;
        e[2 * r2 + 1] = __uint_as_float(u & 0xffff0000u) * inv;
      }
      if (t < 62) {
#pragma unroll
        for (int rq = 0; rq < 4; ++rq) {
          int col0 = kt + 8 * rq + 4 * h;
          *(float4a*)&arow[col0] =
              (float4a){e[4 * rq], e[4 * rq + 1], e[4 * rq + 2], e[4 * rq + 3]};
        }
      } else {
#pragma unroll
        for (int rq = 0; rq < 4; ++rq) {
          int col0 = kt + 8 * rq + 4 * h;
          if (col0 + 3 < NTOK) {
            *(float4a*)&arow[col0] =
                (float4a){e[4 * rq], e[4 * rq + 1], e[4 * rq + 2], e[4 * rq + 3]};
          } else {
#pragma unroll
            for (int j = 0; j < 4; ++j)
              if (col0 + j < NTOK) arow[col0 + j] = e[4 * rq + j];
          }
        }
      }
    }
  }

  // ---- combine partial O across waves via LDS (normalize here) ----
#pragma unroll
  for (int r = 0; r < 16; ++r) {
    int d = (r & 3) + 8 * (r >> 2) + 4 * h;
    s_o[w][d][ql] = oacc0[r];
    s_o[w][d + 32][ql] = oacc1[r];
  }
  __syncthreads();
  {
    int q = tid & 31, dg = tid >> 5;          // 8 d's per thread
    int qg2 = q0 + q;
    if (qg2 < NTOK) {
      float invq = 1.0f / (s_sum[0][q] + s_sum[1][q] + s_sum[2][q] + s_sum[3][q]);
      int b_ = bh >> 2, hd = bh & 3;
      u16* orow = &Ob[((size_t)(b_ * NTOK + qg2)) * 256 + hd * 64 + dg * 8];
      u32 wpk[4];
#pragma unroll
      for (int j = 0; j < 4; ++j) {
        int d = dg * 8 + 2 * j;
        float a = (s_o[0][d][q] + s_o[1][d][q] + s_o[2][d][q] + s_o[3][d][q]) * invq;
        float b = (s_o[0][d + 1][q] + s_o[1][d + 1][q] + s_o[2][d + 1][q] + s_o[3][d + 1][q]) * invq;
        wpk[j] = pk2(a, b);
      }
      *(uint4*)orow = make_uint4(wpk[0], wpk[1], wpk[2], wpk[3]);
    }
  }
}

// ---------------- output GEMM (m97-style): [8036,256] x [1024,256]^T + bias --
__global__ __launch_bounds__(256) void k_gemm_out(
    const u16* __restrict__ A, const u16* __restrict__ Bt,
    const float* __restrict__ bias, float* __restrict__ C)
{
  __shared__ u16 Asm[128 * 64];
  __shared__ u16 Bsm[128 * 64];
  int mt = blockIdx.x * 128, nt = blockIdx.y * 128;
  int tid = threadIdx.x, lane = tid & 63, w = tid >> 6;
  int wm = w >> 1, wn = w & 1;
  int fr = lane & 15, fq = lane >> 4;
  int srow = w * 32 + (lane >> 3);
  int scol = (lane & 7) * 8;
  f32x4 acc[4][4];
#pragma unroll
  for (int a = 0; a < 4; ++a)
#pragma unroll
    for (int b = 0; b < 4; ++b) acc[a][b] = (f32x4){0.f, 0.f, 0.f, 0.f};

  for (int kt = 0; kt < 256; kt += 64) {
#pragma unroll
    for (int j = 0; j < 4; ++j) {
      int r = srow + j * 8;
      int am = mt + r; if (am >= M8) am = 0;
      gload_lds16(A + (size_t)am * 256 + kt + scol, Asm + (size_t)(w * 32 + j * 8) * 64);
      gload_lds16(Bt + (size_t)(nt + r) * 256 + kt + scol, Bsm + (size_t)(w * 32 + j * 8) * 64);
    }
    __syncthreads();
#pragma unroll
    for (int cs = 0; cs < 2; ++cs) {
      short8 af[4], bf[4];
#pragma unroll
      for (int i = 0; i < 4; ++i) {
        af[i] = *(const short8*)&Asm[(size_t)(wm * 64 + i * 16 + fr) * 64 + cs * 32 + fq * 8];
        bf[i] = *(const short8*)&Bsm[(size_t)(wn * 64 + i * 16 + fr) * 64 + cs * 32 + fq * 8];
      }
#pragma unroll
      for (int mi = 0; mi < 4; ++mi)
#pragma unroll
        for (int ni = 0; ni < 4; ++ni)
          acc[mi][ni] = __builtin_amdgcn_mfma_f32_16x16x32_bf16(af[mi], bf[ni], acc[mi][ni], 0, 0, 0);
    }
    __syncthreads();
  }

#pragma unroll
  for (int ni = 0; ni < 4; ++ni) {
    int n = nt + wn * 64 + ni * 16 + fr;
    float bn = bias[n];
#pragma unroll
    for (int mi = 0; mi < 4; ++mi)
#pragma unroll
      for (int i = 0; i < 4; ++i) {
        int m = mt + wm * 64 + mi * 16 + fq * 4 + i;
        if (m < M8) C[(size_t)m * DMOD + n] = acc[mi][ni][i] + bn;
      }
  }
}

extern "C" void kernel_launch(void* const* d_in, const int* in_sizes, int n_in,
                              void* d_out, int out_size, void* d_ws, size_t ws_size,
                              hipStream_t stream) {
  (void)in_sizes; (void)n_in; (void)out_size; (void)ws_size;
  const float* x    = (const float*)d_in[0];
  const float* Wqkv = (const float*)d_in[1];
  const float* Wqs  = (const float*)d_in[2];
  const float* Wout = (const float*)d_in[3];
  const float* bout = (const float*)d_in[4];
  float* out  = (float*)d_out;
  float* attn = out + (size_t)M8 * DMOD;

  char* ws = (char*)d_ws;
  u16*   xb    = (u16*)(ws);                      // 16,515,072 u16 = 33,030,144 B? (no: bytes) 8,257,536 u16 -> 16,515,072 B
  u16*   WtCat = (u16*)(ws + 16515072);           //  2,621,440
  u16*   WtOut = (u16*)(ws + 19136512);           //    524,288
  u16*   Qp    = (u16*)(ws + 19660800);           //  4,128,768
  u16*   Kp    = (u16*)(ws + 23789568);           //  4,128,768
  u16*   Vp    = (u16*)(ws + 27918336);           //  4,128,768
  u16*   Qsb   = (u16*)(ws + 32047104);           //  4,114,432
  u16*   Ksb   = (u16*)(ws + 36161536);           //  4,114,432
  u16*   Ob    = (u16*)(ws + 40275968);           //  4,114,432
  float* selfS = (float*)(ws + 44390400);         //  1,280,000 (end ~45.7 MB)

  k_convs<<<dim3(8064 + 5120 + 1024), dim3(256), 0, stream>>>(
      x, xb, Wqkv, Wqs, WtCat, Wout, WtOut);
  k_gemm_proj<<<dim3(63, 10), dim3(256), 0, stream>>>(xb, WtCat, Qp, Kp, Vp, Qsb, Ksb);
  k_self<<<dim3(3200), dim3(128), 0, stream>>>(Qsb, Ksb, selfS);
  k_attn13<<<dim3(16, 63), dim3(256), 0, stream>>>(Qp, Kp, Vp, selfS, attn, Ob);
  k_gemm_out<<<dim3(63, 8), dim3(256), 0, stream>>>(Ob, WtOut, bout, out);
}

// Round 15
// 186.809 us; speedup vs baseline: 1.3277x; 1.0020x over previous
//
#include <hip/hip_runtime.h>

typedef unsigned short u16;
typedef unsigned int u32;
typedef short short8 __attribute__((ext_vector_type(8)));
typedef float f32x4 __attribute__((ext_vector_type(4)));
typedef float f32x16 __attribute__((ext_vector_type(16)));
typedef float float4a __attribute__((ext_vector_type(4), aligned(4)));

#define NTOK 2009
#define M8   8036      // 4*2009 (real rows)
#define TOKP 2016      // padded tokens per batch (63*32)
#define M8P  8064      // 4*2016 padded rows
#define DMOD 1024
// packed fragment buffers: [bh][tile(63)][...][256] u16; 2048 u16 per tile
#define PKBH 129024    // 63*2048 u16 per bh

static __device__ __forceinline__ u16 f2bf(float f) {
  unsigned int x = __float_as_uint(f);
  x += 0x7fffu + ((x >> 16) & 1u);
  return (u16)(x >> 16);
}
static __device__ __forceinline__ float bf2f(u16 u) {
  return __uint_as_float((unsigned int)u << 16);
}
static __device__ __forceinline__ u32 pk2(float a, float b) {
  return (u32)f2bf(a) | ((u32)f2bf(b) << 16);
}
static __device__ __forceinline__ u32 cvtpk(float a, float b) {
  u32 d;
  asm("v_cvt_pk_bf16_f32 %0, %1, %2" : "=v"(d) : "v"(a), "v"(b));
  return d;
}
static __device__ __forceinline__ void gload_lds16(const void* g, void* l) {
  __builtin_amdgcn_global_load_lds(
      (const __attribute__((address_space(1))) void*)g,
      (__attribute__((address_space(3))) void*)l, 16, 0, 0);
}

// ---------------- merged converts (one launch); xb padded to [4][2016][1024] --
__global__ void k_convs(const float* __restrict__ x, u16* __restrict__ xb,
                        const float* __restrict__ Wqkv, const float* __restrict__ Wqs,
                        u16* __restrict__ WtCat,
                        const float* __restrict__ Wout, u16* __restrict__ WtOut) {
  int blk = blockIdx.x;
  if (blk < 8064) {
    int i = blk * 256 + threadIdx.x;          // uint2 index over padded xb
    int b = i / (TOKP * 256);
    int rem = i - b * (TOKP * 256);
    int tok = rem >> 8, dg = rem & 255;
    uint2 o = make_uint2(0u, 0u);
    if (tok < NTOK) {
      float4 v = ((const float4*)x)[(size_t)(b * NTOK + tok) * 256 + dg];
      o.x = (u32)f2bf(v.x) | ((u32)f2bf(v.y) << 16);
      o.y = (u32)f2bf(v.z) | ((u32)f2bf(v.w) << 16);
    }
    ((uint2*)xb)[i] = o;
  } else if (blk < 8064 + 5120) {
    int i = (blk - 8064) * 256 + threadIdx.x;
    int n = i >> 10, k = i & 1023;
    float v = (n < 768) ? Wqkv[k * 768 + n] : Wqs[k * 512 + (n - 768)];
    WtCat[i] = f2bf(v);
  } else {
    int i = (blk - 8064 - 5120) * 256 + threadIdx.x;
    int n = i >> 8, k = i & 255;
    WtOut[i] = f2bf(Wout[k * 1024 + n]);
  }
}

// ---------------- projection GEMM: [8064,1024] x [1280,1024]^T --------------
// m97-style k-loop; XCD-bijective swizzle (each XCD owns a contiguous m-chunk,
// n fastest -> A chunk stays L2-resident across its 10x reuse). Epilogue
// restages C in LDS then coalesced packed stores (sel-pure blocks, V transposed).
__global__ __launch_bounds__(256) void k_gemm_proj(
    const u16* __restrict__ A, const u16* __restrict__ Bt,
    u16* __restrict__ Qp, u16* __restrict__ Kp, u16* __restrict__ Vp,
    u16* __restrict__ Qsb, u16* __restrict__ Ksb)
{
  __shared__ u16 smem[2][128 * 64];           // A/B staging; reused as C[128][128]
  u16* Asm = smem[0];
  u16* Bsm = smem[1];
  // bijective XCD swizzle: 630 blocks = 6 XCDs x 79 + 2 x 78
  int orig = blockIdx.x + blockIdx.y * 63;
  int xcd = orig & 7, slot = orig >> 3;
  int nid = (xcd < 6 ? xcd * 79 : 474 + (xcd - 6) * 78) + slot;
  int mt = (nid / 10) * 128, nt = (nid % 10) * 128;
  int tid = threadIdx.x, lane = tid & 63, w = tid >> 6;
  int wm = w >> 1, wn = w & 1;
  int fr = lane & 15, fq = lane >> 4;
  int srow = w * 32 + (lane >> 3);
  int scol = (lane & 7) * 8;
  f32x4 acc[4][4];
#pragma unroll
  for (int a = 0; a < 4; ++a)
#pragma unroll
    for (int b = 0; b < 4; ++b) acc[a][b] = (f32x4){0.f, 0.f, 0.f, 0.f};

  for (int kt = 0; kt < 1024; kt += 64) {
#pragma unroll
    for (int j = 0; j < 4; ++j) {
      int r = srow + j * 8;
      gload_lds16(A + (size_t)(mt + r) * 1024 + kt + scol, Asm + (size_t)(w * 32 + j * 8) * 64);
      gload_lds16(Bt + (size_t)(nt + r) * 1024 + kt + scol, Bsm + (size_t)(w * 32 + j * 8) * 64);
    }
    __syncthreads();
#pragma unroll
    for (int cs = 0; cs < 2; ++cs) {
      short8 af[4], bf[4];
#pragma unroll
      for (int i = 0; i < 4; ++i) {
        af[i] = *(const short8*)&Asm[(size_t)(wm * 64 + i * 16 + fr) * 64 + cs * 32 + fq * 8];
        bf[i] = *(const short8*)&Bsm[(size_t)(wn * 64 + i * 16 + fr) * 64 + cs * 32 + fq * 8];
      }
#pragma unroll
      for (int mi = 0; mi < 4; ++mi)
#pragma unroll
        for (int ni = 0; ni < 4; ++ni)
          acc[mi][ni] = __builtin_amdgcn_mfma_f32_16x16x32_bf16(af[mi], bf[ni], acc[mi][ni], 0, 0, 0);
    }
    __syncthreads();
  }

  // ---- epilogue: dump acc to LDS C[128][128] (swizzled), sel-pure block ----
  int sel = nt >> 8;                           // 0=q 1=k 2=v 3=qs 4=ks
  float scl = (sel == 0 || sel == 3) ? 0.0625f : 1.0f;
  bool T = (sel == 2);
  u16* Csm = smem[0];                          // 32 KB = [128][128] u16
#pragma unroll
  for (int ni = 0; ni < 4; ++ni) {
#pragma unroll
    for (int mi = 0; mi < 4; ++mi) {
#pragma unroll
      for (int i = 0; i < 4; ++i) {
        int rm = wm * 64 + mi * 16 + fq * 4 + i;     // m-local
        int cn = wn * 64 + ni * 16 + fr;             // n-local
        u16 val = f2bf(acc[mi][ni][i] * scl);
        if (!T) Csm[rm * 128 + (cn ^ ((rm & 7) << 3))] = val;
        else    Csm[cn * 128 + (rm ^ ((cn & 7) << 3))] = val;
      }
    }
  }
  __syncthreads();

  // ---- coalesced packed write-out: 4 row-groups x 2 head-halves ----------
  int t = tid;
#pragma unroll
  for (int rg = 0; rg < 4; ++rg) {
    int row_g = mt + rg * 32;
    int b_ = row_g / TOKP;
    int tok0 = row_g - b_ * TOKP;
    int tile = tok0 >> 5;
#pragma unroll
    for (int g2 = 0; g2 < 2; ++g2) {
      int g = ((nt + g2 * 64) >> 6);
      int h = g & 3;
      int bh = b_ * 4 + h;
      int Lrow, Lcol0;
      if (sel <= 1) {
        Lrow = rg * 32 + (t & 31);
        Lcol0 = g2 * 64 + (t >> 5) * 8;
        short8 v = *(const short8*)&Csm[Lrow * 128 + (Lcol0 ^ ((Lrow & 7) << 3))];
        u16* dst = (sel == 0 ? Qp : Kp) + ((size_t)bh * 63 + tile) * 2048
                   + (t >> 5) * 256 + (t & 31) * 8;
        *(short8*)dst = v;
      } else if (sel == 2) {
        // transposed dump: Csm[d_local(n)][tok_local(m)]
        Lrow = g2 * 64 + (t >> 7) * 32 + (t & 31);          // n-local (d)
        Lcol0 = rg * 32 + ((t >> 5) & 3) * 8;               // m-local (tok)
        short8 v = *(const short8*)&Csm[Lrow * 128 + (Lcol0 ^ ((Lrow & 7) << 3))];
        u16* dst = Vp + ((size_t)bh * 63 + tile) * 2048 + (t >> 5) * 256 + (t & 31) * 8;
        *(short8*)dst = v;
      } else {
        int tok_l = t >> 3;
        int tok_g = tok0 + tok_l;
        if (tok_g < NTOK) {
          Lrow = rg * 32 + tok_l;
          Lcol0 = g2 * 64 + (t & 7) * 8;
          short8 v = *(const short8*)&Csm[Lrow * 128 + (Lcol0 ^ ((Lrow & 7) << 3))];
          u16* dst = (sel == 3 ? Qsb : Ksb) + ((size_t)bh * NTOK + tok_g) * 64 + (t & 7) * 8;
          *(short8*)dst = v;
        }
      }
    }
  }
}

// ---------------- block-diagonal self dots (Qs pre-scaled, vectorized) -----
__global__ void k_self(const u16* __restrict__ Qs, const u16* __restrict__ Ks,
                       float* __restrict__ selfS) {
  int blk = blockIdx.x;            // bh*200 + agent
  int bh = blk / 200, a = blk % 200;
  int t = threadIdx.x;
  if (t >= 100) return;
  int ri = t / 10, rj = t % 10;
  const short8* qv = (const short8*)&Qs[((size_t)bh * NTOK + a * 10 + ri) * 64];
  const short8* kv = (const short8*)&Ks[((size_t)bh * NTOK + a * 10 + rj) * 64];
  float s = 0.f;
#pragma unroll
  for (int c = 0; c < 8; ++c) {
    short8 qa = qv[c], kb = kv[c];
#pragma unroll
    for (int j = 0; j < 8; ++j) s += bf2f((u16)qa[j]) * bf2f((u16)kb[j]);
  }
  selfS[(size_t)blk * 100 + t] = s;
}

// ---------------- fused attention v13: reg-direct attn stores (frozen) -----
__global__ __launch_bounds__(256, 2) void k_attn13(
    const u16* __restrict__ Qp, const u16* __restrict__ Kp,
    const u16* __restrict__ Vp, const float* __restrict__ selfS,
    float* __restrict__ attn, u16* __restrict__ Ob)
{
  __shared__ float s_sum[4][32];
  __shared__ float s_o[4][64][32];   // 32 KB (O combine only)
  int bh = blockIdx.x;
  int qt = blockIdx.y;
  int q0 = qt * 32;
  int tid = threadIdx.x;
  int lane = tid & 63, w = tid >> 6;
  int ql = lane & 31, h = lane >> 5;
  int qg = q0 + ql;
  bool qok = qg < NTOK;
  int qc = qok ? qg : NTOK - 1;
  int lo8 = ql * 8;

  const u16* qbase = Qp + (size_t)bh * PKBH + (size_t)qt * 2048;
  const u16* kbase = Kp + (size_t)bh * PKBH;
  const u16* vbase = Vp + (size_t)bh * PKBH;

  short8 qf[4];
#pragma unroll
  for (int c = 0; c < 4; ++c)
    qf[c] = *(const short8*)&qbase[(c * 2 + h) * 256 + lo8];

  // block-diagonal patch band
  int qa = (qg < 2000) ? (qg / 10) : -1;
  int band_lo = 1 << 30, band_hi = -(1 << 30);
  if (q0 < 2000) {
    int hi_row = (q0 + 31 < 1999) ? q0 + 31 : 1999;
    band_lo = (q0 / 10) * 10;
    band_hi = (hi_row / 10) * 10 + 10;
  }
  const float* sfb = &selfS[(size_t)bh * 20000];

  int t0 = w * 16;
  int t1 = t0 + 16; if (t1 > 63) t1 = 63;

  u32 pb[16][8];                 // packed unnormalized e (bf16 pairs)
  short8 kf[4], kfn[4], vf[4];
  f32x16 oacc0 = {}, oacc1 = {};

  // ====== loop 1: loads + QK + exp + pack + PV (no global stores) ========
#pragma unroll
  for (int c = 0; c < 4; ++c)
    kf[c] = *(const short8*)&kbase[(size_t)t0 * 2048 + (c * 2 + h) * 256 + lo8];
  float ssum = 0.f;
#pragma unroll
  for (int i = 0; i < 16; ++i) {
    int t = t0 + i;
    if (t < t1) {
      int tn = (t + 1 < t1) ? t + 1 : t0;
#pragma unroll
      for (int c = 0; c < 4; ++c)
        vf[c] = *(const short8*)&vbase[(size_t)t * 2048 + (c * 2 + h) * 256 + lo8];
#pragma unroll
      for (int c = 0; c < 4; ++c)
        kfn[c] = *(const short8*)&kbase[(size_t)tn * 2048 + (c * 2 + h) * 256 + lo8];
      f32x16 acc = {};
#pragma unroll
      for (int c = 0; c < 4; ++c)
        acc = __builtin_amdgcn_mfma_f32_32x32x16_bf16(kf[c], qf[c], acc, 0, 0, 0);
      int kt = t * 32;
      float e[16];
      if ((kt < band_hi) && (kt + 32 > band_lo)) {
#pragma unroll
        for (int r = 0; r < 16; ++r) {
          int kc = kt + (r & 3) + 8 * (r >> 2) + 4 * h;
          float sc = acc[r];
          if (qa >= 0 && kc < 2000 && (kc / 10) == qa)
            sc = sfb[qa * 100 + (qg - qa * 10) * 10 + (kc - qa * 10)];
          e[r] = __expf(sc);
        }
      } else {
#pragma unroll
        for (int r = 0; r < 16; ++r) e[r] = __expf(acc[r]);
      }
      if (t == 62) {             // mask k-pad [2009,2016)
#pragma unroll
        for (int r = 0; r < 16; ++r) {
          int kc = kt + (r & 3) + 8 * (r >> 2) + 4 * h;
          if (kc >= NTOK) e[r] = 0.f;
        }
      }
#pragma unroll
      for (int r2 = 0; r2 < 8; ++r2) {
        pb[i][r2] = cvtpk(e[2 * r2], e[2 * r2 + 1]);
        ssum += e[2 * r2] + e[2 * r2 + 1];
      }
      // ---- redistribute pb -> PV B-fragments; PV accumulate ----
      u32 p00 = __shfl_xor(pb[i][0], 32), p01 = __shfl_xor(pb[i][1], 32);
      u32 p10 = __shfl_xor(pb[i][2], 32), p11 = __shfl_xor(pb[i][3], 32);
      u32 p20 = __shfl_xor(pb[i][4], 32), p21 = __shfl_xor(pb[i][5], 32);
      u32 p30 = __shfl_xor(pb[i][6], 32), p31 = __shfl_xor(pb[i][7], 32);
      u32 b0[4], b1[4];
      b0[0] = h ? p10 : pb[i][0];  b0[1] = h ? p11 : pb[i][1];
      b0[2] = h ? pb[i][2] : p00;  b0[3] = h ? pb[i][3] : p01;
      b1[0] = h ? p30 : pb[i][4];  b1[1] = h ? p31 : pb[i][5];
      b1[2] = h ? pb[i][6] : p20;  b1[3] = h ? pb[i][7] : p21;
      short8 B0, B1;
      __builtin_memcpy(&B0, b0, 16);
      __builtin_memcpy(&B1, b1, 16);
      oacc0 = __builtin_amdgcn_mfma_f32_32x32x16_bf16(vf[0], B0, oacc0, 0, 0, 0);
      oacc1 = __builtin_amdgcn_mfma_f32_32x32x16_bf16(vf[2], B0, oacc1, 0, 0, 0);
      oacc0 = __builtin_amdgcn_mfma_f32_32x32x16_bf16(vf[1], B1, oacc0, 0, 0, 0);
      oacc1 = __builtin_amdgcn_mfma_f32_32x32x16_bf16(vf[3], B1, oacc1, 0, 0, 0);
#pragma unroll
      for (int c = 0; c < 4; ++c) kf[c] = kfn[c];
    }
  }
  ssum += __shfl_xor(ssum, 32);
  if (lane < 32) s_sum[w][ql] = ssum;
  __syncthreads();
  float inv = 1.0f / (s_sum[0][ql] + s_sum[1][ql] + s_sum[2][ql] + s_sum[3][ql]);

  // ====== loop 2: direct-from-register store stream ======================
  float* arow = &attn[((size_t)bh * NTOK + qc) * NTOK];
#pragma unroll
  for (int i = 0; i < 16; ++i) {
    int t = t0 + i;
    if (t < t1 && qok) {
      int kt = t * 32;
      float e[16];
#pragma unroll
      for (int r2 = 0; r2 < 8; ++r2) {
        u32 u = pb[i][r2];
        e[2 * r2]     = __uint_as_float(u << 16) * inv;
        e[2 * r2 + 1] = __uint_as_float(u & 0xffff0000u) * inv;
      }
      if (t < 62) {
#pragma unroll
        for (int rq = 0; rq < 4; ++rq) {
          int col0 = kt + 8 * rq + 4 * h;
          *(float4a*)&arow[col0] =
              (float4a){e[4 * rq], e[4 * rq + 1], e[4 * rq + 2], e[4 * rq + 3]};
        }
      } else {
#pragma unroll
        for (int rq = 0; rq < 4; ++rq) {
          int col0 = kt + 8 * rq + 4 * h;
          if (col0 + 3 < NTOK) {
            *(float4a*)&arow[col0] =
                (float4a){e[4 * rq], e[4 * rq + 1], e[4 * rq + 2], e[4 * rq + 3]};
          } else {
#pragma unroll
            for (int j = 0; j < 4; ++j)
              if (col0 + j < NTOK) arow[col0 + j] = e[4 * rq + j];
          }
        }
      }
    }
  }

  // ---- combine partial O across waves via LDS (normalize here) ----
#pragma unroll
  for (int r = 0; r < 16; ++r) {
    int d = (r & 3) + 8 * (r >> 2) + 4 * h;
    s_o[w][d][ql] = oacc0[r];
    s_o[w][d + 32][ql] = oacc1[r];
  }
  __syncthreads();
  {
    int q = tid & 31, dg = tid >> 5;          // 8 d's per thread
    int qg2 = q0 + q;
    if (qg2 < NTOK) {
      float invq = 1.0f / (s_sum[0][q] + s_sum[1][q] + s_sum[2][q] + s_sum[3][q]);
      int b_ = bh >> 2, hd = bh & 3;
      u16* orow = &Ob[((size_t)(b_ * NTOK + qg2)) * 256 + hd * 64 + dg * 8];
      u32 wpk[4];
#pragma unroll
      for (int j = 0; j < 4; ++j) {
        int d = dg * 8 + 2 * j;
        float a = (s_o[0][d][q] + s_o[1][d][q] + s_o[2][d][q] + s_o[3][d][q]) * invq;
        float b = (s_o[0][d + 1][q] + s_o[1][d + 1][q] + s_o[2][d + 1][q] + s_o[3][d + 1][q]) * invq;
        wpk[j] = pk2(a, b);
      }
      *(uint4*)orow = make_uint4(wpk[0], wpk[1], wpk[2], wpk[3]);
    }
  }
}

// ---------------- output GEMM (m97-style): [8036,256] x [1024,256]^T + bias --
// XCD-bijective swizzle: 504 blocks = 8 x 63; each XCD owns an m-chunk.
__global__ __launch_bounds__(256) void k_gemm_out(
    const u16* __restrict__ A, const u16* __restrict__ Bt,
    const float* __restrict__ bias, float* __restrict__ C)
{
  __shared__ u16 Asm[128 * 64];
  __shared__ u16 Bsm[128 * 64];
  int orig = blockIdx.x + blockIdx.y * 63;
  int xcd = orig & 7, slot = orig >> 3;
  int nid = xcd * 63 + slot;
  int mt = (nid >> 3) * 128, nt = (nid & 7) * 128;
  int tid = threadIdx.x, lane = tid & 63, w = tid >> 6;
  int wm = w >> 1, wn = w & 1;
  int fr = lane & 15, fq = lane >> 4;
  int srow = w * 32 + (lane >> 3);
  int scol = (lane & 7) * 8;
  f32x4 acc[4][4];
#pragma unroll
  for (int a = 0; a < 4; ++a)
#pragma unroll
    for (int b = 0; b < 4; ++b) acc[a][b] = (f32x4){0.f, 0.f, 0.f, 0.f};

  for (int kt = 0; kt < 256; kt += 64) {
#pragma unroll
    for (int j = 0; j < 4; ++j) {
      int r = srow + j * 8;
      int am = mt + r; if (am >= M8) am = 0;
      gload_lds16(A + (size_t)am * 256 + kt + scol, Asm + (size_t)(w * 32 + j * 8) * 64);
      gload_lds16(Bt + (size_t)(nt + r) * 256 + kt + scol, Bsm + (size_t)(w * 32 + j * 8) * 64);
    }
    __syncthreads();
#pragma unroll
    for (int cs = 0; cs < 2; ++cs) {
      short8 af[4], bf[4];
#pragma unroll
      for (int i = 0; i < 4; ++i) {
        af[i] = *(const short8*)&Asm[(size_t)(wm * 64 + i * 16 + fr) * 64 + cs * 32 + fq * 8];
        bf[i] = *(const short8*)&Bsm[(size_t)(wn * 64 + i * 16 + fr) * 64 + cs * 32 + fq * 8];
      }
#pragma unroll
      for (int mi = 0; mi < 4; ++mi)
#pragma unroll
        for (int ni = 0; ni < 4; ++ni)
          acc[mi][ni] = __builtin_amdgcn_mfma_f32_16x16x32_bf16(af[mi], bf[ni], acc[mi][ni], 0, 0, 0);
    }
    __syncthreads();
  }

#pragma unroll
  for (int ni = 0; ni < 4; ++ni) {
    int n = nt + wn * 64 + ni * 16 + fr;
    float bn = bias[n];
#pragma unroll
    for (int mi = 0; mi < 4; ++mi)
#pragma unroll
      for (int i = 0; i < 4; ++i) {
        int m = mt + wm * 64 + mi * 16 + fq * 4 + i;
        if (m < M8) C[(size_t)m * DMOD + n] = acc[mi][ni][i] + bn;
      }
  }
}

extern "C" void kernel_launch(void* const* d_in, const int* in_sizes, int n_in,
                              void* d_out, int out_size, void* d_ws, size_t ws_size,
                              hipStream_t stream) {
  (void)in_sizes; (void)n_in; (void)out_size; (void)ws_size;
  const float* x    = (const float*)d_in[0];
  const float* Wqkv = (const float*)d_in[1];
  const float* Wqs  = (const float*)d_in[2];
  const float* Wout = (const float*)d_in[3];
  const float* bout = (const float*)d_in[4];
  float* out  = (float*)d_out;
  float* attn = out + (size_t)M8 * DMOD;

  char* ws = (char*)d_ws;
  u16*   xb    = (u16*)(ws);                      // 16,515,072 B (padded)
  u16*   WtCat = (u16*)(ws + 16515072);           //  2,621,440
  u16*   WtOut = (u16*)(ws + 19136512);           //    524,288
  u16*   Qp    = (u16*)(ws + 19660800);           //  4,128,768
  u16*   Kp    = (u16*)(ws + 23789568);           //  4,128,768
  u16*   Vp    = (u16*)(ws + 27918336);           //  4,128,768
  u16*   Qsb   = (u16*)(ws + 32047104);           //  4,114,432
  u16*   Ksb   = (u16*)(ws + 36161536);           //  4,114,432
  u16*   Ob    = (u16*)(ws + 40275968);           //  4,114,432
  float* selfS = (float*)(ws + 44390400);         //  1,280,000 (end ~45.7 MB)

  k_convs<<<dim3(8064 + 5120 + 1024), dim3(256), 0, stream>>>(
      x, xb, Wqkv, Wqs, WtCat, Wout, WtOut);
  k_gemm_proj<<<dim3(63, 10), dim3(256), 0, stream>>>(xb, WtCat, Qp, Kp, Vp, Qsb, Ksb);
  k_self<<<dim3(3200), dim3(128), 0, stream>>>(Qsb, Ksb, selfS);
  k_attn13<<<dim3(16, 63), dim3(256), 0, stream>>>(Qp, Kp, Vp, selfS, attn, Ob);
  k_gemm_out<<<dim3(63, 8), dim3(256), 0, stream>>>(Ob, WtOut, bout, out);
}